// Round 5
// baseline (470.341 us; speedup 1.0000x reference)
//
#include <hip/hip_runtime.h>
#include <hip/hip_bf16.h>

// Problem constants
#define N_ROWS 8192
#define F_DIM  512
#define D_DIM  64
#define C_CODES 8192

// ---------------------------------------------------------------------------
// K0: zero the loss accumulator (ws is poisoned 0xAA each call)
__global__ void k_init(float* __restrict__ loss) { loss[0] = 0.0f; }

// ---------------------------------------------------------------------------
// K1: zn = normalise(z @ W_in + b_in)   [8192 x 64]
// 256 blocks x 256 threads; block = 32 rows; K=512 in chunks of 64.
__global__ __launch_bounds__(256) void k_zn(
    const float* __restrict__ z, const float* __restrict__ W_in,
    const float* __restrict__ b_in, float* __restrict__ zn) {
  __shared__ float z_lds[32 * 68];   // [row][k], stride 68 (16B-aligned b128 reads)
  __shared__ float w_lds[64 * 66];   // [col][k], stride 66 (b64 reads, 2-way max)
  const int tid = threadIdx.x;
  const int row0 = blockIdx.x * 32;
  const int rg = tid >> 5;          // 0..7 -> rows rg*4..rg*4+3
  const int cg = tid & 31;          // cols cg, cg+32
  float acc[4][2] = {};

  for (int kk = 0; kk < F_DIM; kk += 64) {
    __syncthreads();
    {  // stage z tile [32 rows][64 k]
      int r = tid >> 3, j = tid & 7;
      const float* src = z + (size_t)(row0 + r) * F_DIM + kk + j * 8;
      float4 a = *(const float4*)src, b = *(const float4*)(src + 4);
      float* dst = z_lds + r * 68 + j * 8;
      *(float4*)dst = a; *(float4*)(dst + 4) = b;
    }
    {  // stage W_in chunk transposed -> [col][k]
      int m = tid & 15;      // col group (4 cols)
      int kb = tid >> 4;     // 0..15
      for (int p = 0; p < 4; ++p) {
        int k = p * 16 + kb;
        float4 wv = *(const float4*)(W_in + (size_t)(kk + k) * D_DIM + m * 4);
        w_lds[(m * 4 + 0) * 66 + k] = wv.x;
        w_lds[(m * 4 + 1) * 66 + k] = wv.y;
        w_lds[(m * 4 + 2) * 66 + k] = wv.z;
        w_lds[(m * 4 + 3) * 66 + k] = wv.w;
      }
    }
    __syncthreads();
    for (int k = 0; k < 64; k += 4) {
      float4 zv[4];
      #pragma unroll
      for (int r = 0; r < 4; ++r)
        zv[r] = *(const float4*)(z_lds + (rg * 4 + r) * 68 + k);
      #pragma unroll
      for (int j = 0; j < 2; ++j) {
        const float* wp = w_lds + (cg + 32 * j) * 66 + k;
        float2 w0 = *(const float2*)wp, w1 = *(const float2*)(wp + 2);
        #pragma unroll
        for (int r = 0; r < 4; ++r)
          acc[r][j] += zv[r].x * w0.x + zv[r].y * w0.y + zv[r].z * w1.x + zv[r].w * w1.y;
      }
    }
  }

  // epilogue: bias, write zp into LDS, row-normalize, store zn
  __syncthreads();
  #pragma unroll
  for (int j = 0; j < 2; ++j) {
    int col = cg + 32 * j;
    float b = b_in[col];
    #pragma unroll
    for (int r = 0; r < 4; ++r)
      z_lds[(rg * 4 + r) * 68 + col] = acc[r][j] + b;
  }
  __syncthreads();
  {
    int r = tid >> 3, j = tid & 7;
    const float* rowp = z_lds + r * 68;
    float s = 0.0f;
    #pragma unroll
    for (int q = 0; q < 8; ++q) { float v = rowp[j * 8 + q]; s += v * v; }
    s += __shfl_xor(s, 1);
    s += __shfl_xor(s, 2);
    s += __shfl_xor(s, 4);
    float inv = rsqrtf(s * (1.0f / 64.0f) + 1e-12f);
    const float* sp = rowp + j * 8;
    float* dst = zn + (size_t)(row0 + r) * D_DIM + j * 8;
    float4 o0 = make_float4(sp[0] * inv, sp[1] * inv, sp[2] * inv, sp[3] * inv);
    float4 o1 = make_float4(sp[4] * inv, sp[5] * inv, sp[6] * inv, sp[7] * inv);
    *(float4*)dst = o0; *(float4*)(dst + 4) = o1;
  }
}

// ---------------------------------------------------------------------------
// K2: cn = normalise(codebook)  [8192 x 64]; one wave per row
__global__ __launch_bounds__(256) void k_cn(
    const float* __restrict__ cb, float* __restrict__ cn) {
  int row = blockIdx.x * 4 + (threadIdx.x >> 6);
  int lane = threadIdx.x & 63;
  float v = cb[(size_t)row * D_DIM + lane];
  float s = v * v;
  #pragma unroll
  for (int m = 1; m < 64; m <<= 1) s += __shfl_xor(s, m);
  float inv = rsqrtf(s * (1.0f / 64.0f) + 1e-12f);
  cn[(size_t)row * D_DIM + lane] = v * inv;
}

// ---------------------------------------------------------------------------
// K3: per row argmax over codes of zn . cn  (== argmin distance)
// 256 blocks x 256 threads; block = 32 rows; codes chunked 128 at a time.
__global__ __launch_bounds__(256) void k_argmax(
    const float* __restrict__ zn, const float* __restrict__ cn,
    int* __restrict__ idx_out, float* __restrict__ idx_f) {
  __shared__ float cn_lds[128 * 66];  // [code][k], stride 66
  __shared__ float zn_lds[32 * 68];   // [row][k],  stride 68
  const int tid = threadIdx.x;
  const int row0 = blockIdx.x * 32;
  const int rg = tid >> 5, cg = tid & 31;

  {  // stage zn rows once
    int r = tid >> 3, j = tid & 7;
    const float* src = zn + (size_t)(row0 + r) * D_DIM + j * 8;
    float4 a = *(const float4*)src, b = *(const float4*)(src + 4);
    float* dst = zn_lds + r * 68 + j * 8;
    *(float4*)dst = a; *(float4*)(dst + 4) = b;
  }

  float best_v[4] = {-1e30f, -1e30f, -1e30f, -1e30f};
  int best_i[4] = {0, 0, 0, 0};

  for (int c0 = 0; c0 < C_CODES; c0 += 128) {
    __syncthreads();
    {  // stage 128 codes x 64 (coalesced: 16 lanes per code row)
      #pragma unroll
      for (int p = 0; p < 8; ++p) {
        int f = p * 256 + tid;        // float4 id 0..2047
        int code = f >> 4, quad = f & 15;
        float4 v = *(const float4*)(cn + (size_t)(c0 + code) * D_DIM + quad * 4);
        float* dst = cn_lds + code * 66 + quad * 4;
        *(float2*)dst = make_float2(v.x, v.y);
        *(float2*)(dst + 2) = make_float2(v.z, v.w);
      }
    }
    __syncthreads();
    float acc[4][4] = {};
    for (int k = 0; k < 64; k += 4) {
      float4 zv[4];
      #pragma unroll
      for (int r = 0; r < 4; ++r)
        zv[r] = *(const float4*)(zn_lds + (rg * 4 + r) * 68 + k);
      #pragma unroll
      for (int j = 0; j < 4; ++j) {
        const float* cp = cn_lds + (cg + 32 * j) * 66 + k;
        float2 a0 = *(const float2*)cp, a1 = *(const float2*)(cp + 2);
        #pragma unroll
        for (int r = 0; r < 4; ++r)
          acc[r][j] += zv[r].x * a0.x + zv[r].y * a0.y + zv[r].z * a1.x + zv[r].w * a1.y;
      }
    }
    #pragma unroll
    for (int j = 0; j < 4; ++j) {
      int idx = c0 + cg + 32 * j;
      #pragma unroll
      for (int r = 0; r < 4; ++r) {
        if (acc[r][j] > best_v[r]) { best_v[r] = acc[r][j]; best_i[r] = idx; }
      }
    }
  }

  // cross-lane reduce over the 32 threads sharing each row group
  #pragma unroll
  for (int r = 0; r < 4; ++r) {
    float v = best_v[r]; int i = best_i[r];
    for (int m = 1; m < 32; m <<= 1) {
      float ov = __shfl_xor(v, m);
      int oi = __shfl_xor(i, m);
      if (ov > v || (ov == v && oi < i)) { v = ov; i = oi; }
    }
    if (cg == 0) {
      int row = row0 + rg * 4 + r;
      idx_out[row] = i;
      idx_f[row] = (float)i;
    }
  }
}

// ---------------------------------------------------------------------------
// K4: out = cn[idx] @ W_out + b_out  (float32 store)  +  loss partial sums
// 256 blocks x 256 threads; block = 32 rows; 512 cols in 4 quarters of 128.
__global__ __launch_bounds__(256) void k_out(
    const float* __restrict__ cn, const float* __restrict__ zn,
    const int* __restrict__ idx, const float* __restrict__ W_out,
    const float* __restrict__ b_out, float* __restrict__ out,
    float* __restrict__ loss_acc) {
  __shared__ float w_lds[128 * 66];  // [col][k] for current quarter
  __shared__ float cq_lds[32 * 68];  // [row][k]
  const int tid = threadIdx.x;
  const int row0 = blockIdx.x * 32;
  const int rg = tid >> 5, cg = tid & 31;

  // gather cq rows + loss partial
  float lp = 0.0f;
  {
    int r = tid >> 3, j = tid & 7;
    int code = idx[row0 + r];
    const float* src = cn + (size_t)code * D_DIM + j * 8;
    const float* zsrc = zn + (size_t)(row0 + r) * D_DIM + j * 8;
    float4 a = *(const float4*)src, b = *(const float4*)(src + 4);
    float4 za = *(const float4*)zsrc, zb = *(const float4*)(zsrc + 4);
    float* dst = cq_lds + r * 68 + j * 8;
    *(float4*)dst = a; *(float4*)(dst + 4) = b;
    float dx = a.x - za.x, dy = a.y - za.y, dz = a.z - za.z, dw = a.w - za.w;
    lp = dx * dx + dy * dy + dz * dz + dw * dw;
    dx = b.x - zb.x; dy = b.y - zb.y; dz = b.z - zb.z; dw = b.w - zb.w;
    lp += dx * dx + dy * dy + dz * dz + dw * dw;
  }
  #pragma unroll
  for (int m = 1; m < 64; m <<= 1) lp += __shfl_xor(lp, m);
  if ((tid & 63) == 0) atomicAdd(loss_acc, lp);

  for (int q = 0; q < 4; ++q) {
    __syncthreads();
    {  // stage W_out quarter transposed -> [col][k]
      int m = tid & 31;    // col4 group
      int kb = tid >> 5;   // 0..7
      for (int p = 0; p < 8; ++p) {
        int k = p * 8 + kb;
        float4 wv = *(const float4*)(W_out + (size_t)k * F_DIM + q * 128 + m * 4);
        w_lds[(m * 4 + 0) * 66 + k] = wv.x;
        w_lds[(m * 4 + 1) * 66 + k] = wv.y;
        w_lds[(m * 4 + 2) * 66 + k] = wv.z;
        w_lds[(m * 4 + 3) * 66 + k] = wv.w;
      }
    }
    __syncthreads();
    float acc[4][4] = {};
    for (int k = 0; k < 64; k += 4) {
      float4 av[4];
      #pragma unroll
      for (int r = 0; r < 4; ++r)
        av[r] = *(const float4*)(cq_lds + (rg * 4 + r) * 68 + k);
      #pragma unroll
      for (int j = 0; j < 4; ++j) {
        const float* wp = w_lds + (cg + 32 * j) * 66 + k;
        float2 w0 = *(const float2*)wp, w1 = *(const float2*)(wp + 2);
        #pragma unroll
        for (int r = 0; r < 4; ++r)
          acc[r][j] += av[r].x * w0.x + av[r].y * w0.y + av[r].z * w1.x + av[r].w * w1.y;
      }
    }
    #pragma unroll
    for (int j = 0; j < 4; ++j) {
      int col = q * 128 + cg + 32 * j;
      float b = b_out[col];
      #pragma unroll
      for (int r = 0; r < 4; ++r) {
        int row = row0 + rg * 4 + r;
        out[(size_t)row * F_DIM + col] = acc[r][j] + b;
      }
    }
  }
}

// ---------------------------------------------------------------------------
// K5: finalize loss -> float32
__global__ void k_loss_final(const float* __restrict__ loss,
                             float* __restrict__ out) {
  out[0] = loss[0] * (1.25f / (float)(N_ROWS * D_DIM));
}

// ---------------------------------------------------------------------------
extern "C" void kernel_launch(void* const* d_in, const int* in_sizes, int n_in,
                              void* d_out, int out_size, void* d_ws, size_t ws_size,
                              hipStream_t stream) {
  const float* z        = (const float*)d_in[0];
  const float* W_in     = (const float*)d_in[1];
  const float* b_in     = (const float*)d_in[2];
  const float* codebook = (const float*)d_in[3];
  const float* W_out    = (const float*)d_in[4];
  const float* b_out    = (const float*)d_in[5];

  float* outp   = (float*)d_out;                      // Output 0: [8192 x 512]
  float* loss_f = outp + (size_t)N_ROWS * F_DIM;      // Output 1: element 4194304
  float* idx_f  = loss_f + 1;                         // Output 2: elements 4194305..

  float* wsf = (float*)d_ws;
  float* zn_ws = wsf;                       // 524288 floats
  float* cn_ws = wsf + 524288;              // 524288 floats
  float* loss_ws = wsf + 1048576;           // 1 float
  int*   idx_ws = (int*)(wsf + 1048592);    // 8192 ints

  hipLaunchKernelGGL(k_init, dim3(1), dim3(1), 0, stream, loss_ws);
  hipLaunchKernelGGL(k_zn, dim3(N_ROWS / 32), dim3(256), 0, stream,
                     z, W_in, b_in, zn_ws);
  hipLaunchKernelGGL(k_cn, dim3(C_CODES / 4), dim3(256), 0, stream,
                     codebook, cn_ws);
  hipLaunchKernelGGL(k_argmax, dim3(N_ROWS / 32), dim3(256), 0, stream,
                     zn_ws, cn_ws, idx_ws, idx_f);
  hipLaunchKernelGGL(k_out, dim3(N_ROWS / 32), dim3(256), 0, stream,
                     cn_ws, zn_ws, idx_ws, W_out, b_out, outp, loss_ws);
  hipLaunchKernelGGL(k_loss_final, dim3(1), dim3(1), 0, stream,
                     loss_ws, loss_f);
}

// Round 6
// 309.983 us; speedup vs baseline: 1.5173x; 1.5173x over previous
//
#include <hip/hip_runtime.h>
#include <hip/hip_bf16.h>

// Problem constants
#define N_ROWS 8192
#define F_DIM  512
#define D_DIM  64
#define C_CODES 8192

// ---------------------------------------------------------------------------
// Quad-lane butterfly via DPP (VALU, not LDS unit).
// quad_perm encodings: xor1 = [1,0,3,2] = 0xB1 ; xor2 = [2,3,0,1] = 0x4E
__device__ __forceinline__ float qxor1(float x) {
  return __int_as_float(__builtin_amdgcn_mov_dpp(__float_as_int(x), 0xB1, 0xF, 0xF, true));
}
__device__ __forceinline__ float qxor2(float x) {
  return __int_as_float(__builtin_amdgcn_mov_dpp(__float_as_int(x), 0x4E, 0xF, 0xF, true));
}

// ---------------------------------------------------------------------------
// K0: zero the loss accumulator (ws is poisoned 0xAA each call)
__global__ void k_init(float* __restrict__ loss) { loss[0] = 0.0f; }

// ---------------------------------------------------------------------------
// K1: zn = normalise(z @ W_in + b_in)   [8192 x 64]
__global__ __launch_bounds__(256) void k_zn(
    const float* __restrict__ z, const float* __restrict__ W_in,
    const float* __restrict__ b_in, float* __restrict__ zn) {
  __shared__ float z_lds[32 * 68];
  __shared__ float w_lds[64 * 66];
  const int tid = threadIdx.x;
  const int row0 = blockIdx.x * 32;
  const int rg = tid >> 5;
  const int cg = tid & 31;
  float acc[4][2] = {};

  for (int kk = 0; kk < F_DIM; kk += 64) {
    __syncthreads();
    {
      int r = tid >> 3, j = tid & 7;
      const float* src = z + (size_t)(row0 + r) * F_DIM + kk + j * 8;
      float4 a = *(const float4*)src, b = *(const float4*)(src + 4);
      float* dst = z_lds + r * 68 + j * 8;
      *(float4*)dst = a; *(float4*)(dst + 4) = b;
    }
    {
      int m = tid & 15;
      int kb = tid >> 4;
      for (int p = 0; p < 4; ++p) {
        int k = p * 16 + kb;
        float4 wv = *(const float4*)(W_in + (size_t)(kk + k) * D_DIM + m * 4);
        w_lds[(m * 4 + 0) * 66 + k] = wv.x;
        w_lds[(m * 4 + 1) * 66 + k] = wv.y;
        w_lds[(m * 4 + 2) * 66 + k] = wv.z;
        w_lds[(m * 4 + 3) * 66 + k] = wv.w;
      }
    }
    __syncthreads();
    for (int k = 0; k < 64; k += 4) {
      float4 zv[4];
      #pragma unroll
      for (int r = 0; r < 4; ++r)
        zv[r] = *(const float4*)(z_lds + (rg * 4 + r) * 68 + k);
      #pragma unroll
      for (int j = 0; j < 2; ++j) {
        const float* wp = w_lds + (cg + 32 * j) * 66 + k;
        float2 w0 = *(const float2*)wp, w1 = *(const float2*)(wp + 2);
        #pragma unroll
        for (int r = 0; r < 4; ++r)
          acc[r][j] += zv[r].x * w0.x + zv[r].y * w0.y + zv[r].z * w1.x + zv[r].w * w1.y;
      }
    }
  }

  __syncthreads();
  #pragma unroll
  for (int j = 0; j < 2; ++j) {
    int col = cg + 32 * j;
    float b = b_in[col];
    #pragma unroll
    for (int r = 0; r < 4; ++r)
      z_lds[(rg * 4 + r) * 68 + col] = acc[r][j] + b;
  }
  __syncthreads();
  {
    int r = tid >> 3, j = tid & 7;
    const float* rowp = z_lds + r * 68;
    float s = 0.0f;
    #pragma unroll
    for (int q = 0; q < 8; ++q) { float v = rowp[j * 8 + q]; s += v * v; }
    s += __shfl_xor(s, 1);
    s += __shfl_xor(s, 2);
    s += __shfl_xor(s, 4);
    float inv = rsqrtf(s * (1.0f / 64.0f) + 1e-12f);
    const float* sp = rowp + j * 8;
    float* dst = zn + (size_t)(row0 + r) * D_DIM + j * 8;
    float4 o0 = make_float4(sp[0] * inv, sp[1] * inv, sp[2] * inv, sp[3] * inv);
    float4 o1 = make_float4(sp[4] * inv, sp[5] * inv, sp[6] * inv, sp[7] * inv);
    *(float4*)dst = o0; *(float4*)(dst + 4) = o1;
  }
}

// ---------------------------------------------------------------------------
// K2: cn = normalise(codebook)  [8192 x 64]; one wave per row
__global__ __launch_bounds__(256) void k_cn(
    const float* __restrict__ cb, float* __restrict__ cn) {
  int row = blockIdx.x * 4 + (threadIdx.x >> 6);
  int lane = threadIdx.x & 63;
  float v = cb[(size_t)row * D_DIM + lane];
  float s = v * v;
  #pragma unroll
  for (int m = 1; m < 64; m <<= 1) s += __shfl_xor(s, m);
  float inv = rsqrtf(s * (1.0f / 64.0f) + 1e-12f);
  cn[(size_t)row * D_DIM + lane] = v * inv;
}

// ---------------------------------------------------------------------------
// K3 v2: LDS-free argmax. Lane layout: q = lane>>2 (code slot 0..15),
// kp = lane&3 (k-quarter). Each lane holds zn[8 rows][kp*16..+16] in regs.
// Per pass: 16 codes; each lane reads 64B of one code from global (L2),
// 128 FMAs, quad-DPP butterfly -> full dots, compare. No __syncthreads.
// Grid (256, 2): y = code half (4096 codes, 256 passes). Partial results
// per half merged by k_merge.
__global__ __launch_bounds__(256, 2) void k_argmax(
    const float* __restrict__ zn, const float* __restrict__ cn,
    float* __restrict__ pval, int* __restrict__ pidx) {
  const int tid = threadIdx.x;
  const int l = tid & 63;
  const int wave = tid >> 6;
  const int q = l >> 2;
  const int kp = l & 3;
  const int r0 = blockIdx.x * 32 + wave * 8;
  const int cb = blockIdx.y * 4096;

  // zn fragment: 8 rows x 16 ks (this lane's k-quarter) = 32 float4 regs
  float4 zr[8][4];
  #pragma unroll
  for (int i = 0; i < 8; ++i) {
    const float4* zp = (const float4*)(zn + (size_t)(r0 + i) * D_DIM + kp * 16);
    #pragma unroll
    for (int u = 0; u < 4; ++u) zr[i][u] = zp[u];
  }

  float bv[8];
  int bi[8];
  #pragma unroll
  for (int i = 0; i < 8; ++i) { bv[i] = -1e30f; bi[i] = 0; }

  const float4* cp = (const float4*)(cn + (size_t)(cb + q) * D_DIM + kp * 16);
  float4 c0 = cp[0], c1 = cp[1], c2 = cp[2], c3 = cp[3];
  int ci = cb + q;

  for (int pass = 0; pass < 256; ++pass) {
    cp += 256;  // 16 codes * 64 floats
    // prefetch next pass (last iteration over-reads 4KB into ws scratch - harmless)
    float4 n0 = cp[0], n1 = cp[1], n2 = cp[2], n3 = cp[3];

    float d[8];
    #pragma unroll
    for (int i = 0; i < 8; ++i) d[i] = 0.0f;
    #pragma unroll
    for (int i = 0; i < 8; ++i)
      d[i] += zr[i][0].x * c0.x + zr[i][0].y * c0.y + zr[i][0].z * c0.z + zr[i][0].w * c0.w;
    #pragma unroll
    for (int i = 0; i < 8; ++i)
      d[i] += zr[i][1].x * c1.x + zr[i][1].y * c1.y + zr[i][1].z * c1.z + zr[i][1].w * c1.w;
    #pragma unroll
    for (int i = 0; i < 8; ++i)
      d[i] += zr[i][2].x * c2.x + zr[i][2].y * c2.y + zr[i][2].z * c2.z + zr[i][2].w * c2.w;
    #pragma unroll
    for (int i = 0; i < 8; ++i)
      d[i] += zr[i][3].x * c3.x + zr[i][3].y * c3.y + zr[i][3].z * c3.z + zr[i][3].w * c3.w;

    #pragma unroll
    for (int i = 0; i < 8; ++i) {
      float t = d[i];
      t += qxor1(t);
      t += qxor2(t);   // full dot now in all 4 quad lanes
      if (t > bv[i]) { bv[i] = t; bi[i] = ci; }
    }
    ci += 16;
    c0 = n0; c1 = n1; c2 = n2; c3 = n3;
  }

  // wave-wide (val, idx) argmax per row; quads already uniform -> masks 4..32
  #pragma unroll
  for (int i = 0; i < 8; ++i) {
    float v = bv[i]; int ix = bi[i];
    #pragma unroll
    for (int m = 4; m < 64; m <<= 1) {
      float ov = __shfl_xor(v, m);
      int oi = __shfl_xor(ix, m);
      if (ov > v || (ov == v && oi < ix)) { v = ov; ix = oi; }
    }
    bv[i] = v; bi[i] = ix;
  }
  if (l == 0) {
    int poff = blockIdx.y * N_ROWS + r0;
    #pragma unroll
    for (int i = 0; i < 8; ++i) { pval[poff + i] = bv[i]; pidx[poff + i] = bi[i]; }
  }
}

// ---------------------------------------------------------------------------
// K3b: merge the two code-half partials. Ties -> half 0 (lower idx) matches
// argmin first-hit semantics.
__global__ __launch_bounds__(256) void k_merge(
    const float* __restrict__ pval, const int* __restrict__ pidx,
    int* __restrict__ idx_out, float* __restrict__ idx_f) {
  int row = blockIdx.x * 256 + threadIdx.x;
  float v0 = pval[row], v1 = pval[N_ROWS + row];
  int i0 = pidx[row], i1 = pidx[N_ROWS + row];
  int ix = (v1 > v0) ? i1 : i0;
  idx_out[row] = ix;
  idx_f[row] = (float)ix;
}

// ---------------------------------------------------------------------------
// K4: out = cn[idx] @ W_out + b_out  (float32 store)  +  loss partial sums
__global__ __launch_bounds__(256) void k_out(
    const float* __restrict__ cn, const float* __restrict__ zn,
    const int* __restrict__ idx, const float* __restrict__ W_out,
    const float* __restrict__ b_out, float* __restrict__ out,
    float* __restrict__ loss_acc) {
  __shared__ float w_lds[128 * 66];
  __shared__ float cq_lds[32 * 68];
  const int tid = threadIdx.x;
  const int row0 = blockIdx.x * 32;
  const int rg = tid >> 5, cg = tid & 31;

  float lp = 0.0f;
  {
    int r = tid >> 3, j = tid & 7;
    int code = idx[row0 + r];
    const float* src = cn + (size_t)code * D_DIM + j * 8;
    const float* zsrc = zn + (size_t)(row0 + r) * D_DIM + j * 8;
    float4 a = *(const float4*)src, b = *(const float4*)(src + 4);
    float4 za = *(const float4*)zsrc, zb = *(const float4*)(zsrc + 4);
    float* dst = cq_lds + r * 68 + j * 8;
    *(float4*)dst = a; *(float4*)(dst + 4) = b;
    float dx = a.x - za.x, dy = a.y - za.y, dz = a.z - za.z, dw = a.w - za.w;
    lp = dx * dx + dy * dy + dz * dz + dw * dw;
    dx = b.x - zb.x; dy = b.y - zb.y; dz = b.z - zb.z; dw = b.w - zb.w;
    lp += dx * dx + dy * dy + dz * dz + dw * dw;
  }
  #pragma unroll
  for (int m = 1; m < 64; m <<= 1) lp += __shfl_xor(lp, m);
  if ((tid & 63) == 0) atomicAdd(loss_acc, lp);

  for (int q = 0; q < 4; ++q) {
    __syncthreads();
    {
      int m = tid & 31;
      int kb = tid >> 5;
      for (int p = 0; p < 8; ++p) {
        int k = p * 8 + kb;
        float4 wv = *(const float4*)(W_out + (size_t)k * F_DIM + q * 128 + m * 4);
        w_lds[(m * 4 + 0) * 66 + k] = wv.x;
        w_lds[(m * 4 + 1) * 66 + k] = wv.y;
        w_lds[(m * 4 + 2) * 66 + k] = wv.z;
        w_lds[(m * 4 + 3) * 66 + k] = wv.w;
      }
    }
    __syncthreads();
    float acc[4][4] = {};
    for (int k = 0; k < 64; k += 4) {
      float4 av[4];
      #pragma unroll
      for (int r = 0; r < 4; ++r)
        av[r] = *(const float4*)(cq_lds + (rg * 4 + r) * 68 + k);
      #pragma unroll
      for (int j = 0; j < 4; ++j) {
        const float* wp = w_lds + (cg + 32 * j) * 66 + k;
        float2 w0 = *(const float2*)wp, w1 = *(const float2*)(wp + 2);
        #pragma unroll
        for (int r = 0; r < 4; ++r)
          acc[r][j] += av[r].x * w0.x + av[r].y * w0.y + av[r].z * w1.x + av[r].w * w1.y;
      }
    }
    #pragma unroll
    for (int j = 0; j < 4; ++j) {
      int col = q * 128 + cg + 32 * j;
      float b = b_out[col];
      #pragma unroll
      for (int r = 0; r < 4; ++r) {
        int row = row0 + rg * 4 + r;
        out[(size_t)row * F_DIM + col] = acc[r][j] + b;
      }
    }
  }
}

// ---------------------------------------------------------------------------
// K5: finalize loss -> float32
__global__ void k_loss_final(const float* __restrict__ loss,
                             float* __restrict__ out) {
  out[0] = loss[0] * (1.25f / (float)(N_ROWS * D_DIM));
}

// ---------------------------------------------------------------------------
extern "C" void kernel_launch(void* const* d_in, const int* in_sizes, int n_in,
                              void* d_out, int out_size, void* d_ws, size_t ws_size,
                              hipStream_t stream) {
  const float* z        = (const float*)d_in[0];
  const float* W_in     = (const float*)d_in[1];
  const float* b_in     = (const float*)d_in[2];
  const float* codebook = (const float*)d_in[3];
  const float* W_out    = (const float*)d_in[4];
  const float* b_out    = (const float*)d_in[5];

  float* outp   = (float*)d_out;                      // Output 0: [8192 x 512]
  float* loss_f = outp + (size_t)N_ROWS * F_DIM;      // Output 1
  float* idx_f  = loss_f + 1;                         // Output 2

  float* wsf = (float*)d_ws;
  float* zn_ws = wsf;                        // 524288 floats
  float* cn_ws = wsf + 524288;               // 524288 floats (ends at 1048576)
  float* loss_ws = wsf + 1048576;            // 1 float
  int*   idx_ws  = (int*)(wsf + 1048592);    // 8192 ints
  float* pval_ws = wsf + 1056784;            // 16384 floats (2 halves x 8192)
  int*   pidx_ws = (int*)(wsf + 1073168);    // 16384 ints

  hipLaunchKernelGGL(k_init, dim3(1), dim3(1), 0, stream, loss_ws);
  hipLaunchKernelGGL(k_zn, dim3(N_ROWS / 32), dim3(256), 0, stream,
                     z, W_in, b_in, zn_ws);
  hipLaunchKernelGGL(k_cn, dim3(C_CODES / 4), dim3(256), 0, stream,
                     codebook, cn_ws);
  hipLaunchKernelGGL(k_argmax, dim3(N_ROWS / 32, 2), dim3(256), 0, stream,
                     zn_ws, cn_ws, pval_ws, pidx_ws);
  hipLaunchKernelGGL(k_merge, dim3(N_ROWS / 256), dim3(256), 0, stream,
                     pval_ws, pidx_ws, idx_ws, idx_f);
  hipLaunchKernelGGL(k_out, dim3(N_ROWS / 32), dim3(256), 0, stream,
                     cn_ws, zn_ws, idx_ws, W_out, b_out, outp, loss_ws);
  hipLaunchKernelGGL(k_loss_final, dim3(1), dim3(1), 0, stream,
                     loss_ws, loss_f);
}

// Round 7
// 222.765 us; speedup vs baseline: 2.1114x; 1.3915x over previous
//
#include <hip/hip_runtime.h>
#include <hip/hip_bf16.h>

// Problem constants
#define N_ROWS 8192
#define F_DIM  512
#define D_DIM  64
#define C_CODES 8192

typedef __attribute__((ext_vector_type(8))) short bf16x8;   // 8 bf16 = 4 VGPRs
typedef __attribute__((ext_vector_type(4))) float f32x4;

// bf16 round-to-nearest-even, manual (no hip_bf16 struct-layout dependence)
__device__ __forceinline__ unsigned short rne_bf16(float x) {
  unsigned u = __float_as_uint(x);
  return (unsigned short)((u + 0x7FFFu + ((u >> 16) & 1u)) >> 16);
}
__device__ __forceinline__ float bf16_to_f(unsigned short u) {
  return __uint_as_float(((unsigned)u) << 16);
}

// ---------------------------------------------------------------------------
// K0: zero the loss accumulator
__global__ void k_init(float* __restrict__ loss) { loss[0] = 0.0f; }

// ---------------------------------------------------------------------------
// K1: zn = normalise(z @ W_in + b_in)   [8192 x 64]  (unchanged from R6)
__global__ __launch_bounds__(256) void k_zn(
    const float* __restrict__ z, const float* __restrict__ W_in,
    const float* __restrict__ b_in, float* __restrict__ zn) {
  __shared__ float z_lds[32 * 68];
  __shared__ float w_lds[64 * 66];
  const int tid = threadIdx.x;
  const int row0 = blockIdx.x * 32;
  const int rg = tid >> 5;
  const int cg = tid & 31;
  float acc[4][2] = {};

  for (int kk = 0; kk < F_DIM; kk += 64) {
    __syncthreads();
    {
      int r = tid >> 3, j = tid & 7;
      const float* src = z + (size_t)(row0 + r) * F_DIM + kk + j * 8;
      float4 a = *(const float4*)src, b = *(const float4*)(src + 4);
      float* dst = z_lds + r * 68 + j * 8;
      *(float4*)dst = a; *(float4*)(dst + 4) = b;
    }
    {
      int m = tid & 15;
      int kb = tid >> 4;
      for (int p = 0; p < 4; ++p) {
        int k = p * 16 + kb;
        float4 wv = *(const float4*)(W_in + (size_t)(kk + k) * D_DIM + m * 4);
        w_lds[(m * 4 + 0) * 66 + k] = wv.x;
        w_lds[(m * 4 + 1) * 66 + k] = wv.y;
        w_lds[(m * 4 + 2) * 66 + k] = wv.z;
        w_lds[(m * 4 + 3) * 66 + k] = wv.w;
      }
    }
    __syncthreads();
    for (int k = 0; k < 64; k += 4) {
      float4 zv[4];
      #pragma unroll
      for (int r = 0; r < 4; ++r)
        zv[r] = *(const float4*)(z_lds + (rg * 4 + r) * 68 + k);
      #pragma unroll
      for (int j = 0; j < 2; ++j) {
        const float* wp = w_lds + (cg + 32 * j) * 66 + k;
        float2 w0 = *(const float2*)wp, w1 = *(const float2*)(wp + 2);
        #pragma unroll
        for (int r = 0; r < 4; ++r)
          acc[r][j] += zv[r].x * w0.x + zv[r].y * w0.y + zv[r].z * w1.x + zv[r].w * w1.y;
      }
    }
  }

  __syncthreads();
  #pragma unroll
  for (int j = 0; j < 2; ++j) {
    int col = cg + 32 * j;
    float b = b_in[col];
    #pragma unroll
    for (int r = 0; r < 4; ++r)
      z_lds[(rg * 4 + r) * 68 + col] = acc[r][j] + b;
  }
  __syncthreads();
  {
    int r = tid >> 3, j = tid & 7;
    const float* rowp = z_lds + r * 68;
    float s = 0.0f;
    #pragma unroll
    for (int q = 0; q < 8; ++q) { float v = rowp[j * 8 + q]; s += v * v; }
    s += __shfl_xor(s, 1);
    s += __shfl_xor(s, 2);
    s += __shfl_xor(s, 4);
    float inv = rsqrtf(s * (1.0f / 64.0f) + 1e-12f);
    const float* sp = rowp + j * 8;
    float* dst = zn + (size_t)(row0 + r) * D_DIM + j * 8;
    float4 o0 = make_float4(sp[0] * inv, sp[1] * inv, sp[2] * inv, sp[3] * inv);
    float4 o1 = make_float4(sp[4] * inv, sp[5] * inv, sp[6] * inv, sp[7] * inv);
    *(float4*)dst = o0; *(float4*)(dst + 4) = o1;
  }
}

// ---------------------------------------------------------------------------
// K2: cn = normalise(codebook)  (unchanged)
__global__ __launch_bounds__(256) void k_cn(
    const float* __restrict__ cb, float* __restrict__ cn) {
  int row = blockIdx.x * 4 + (threadIdx.x >> 6);
  int lane = threadIdx.x & 63;
  float v = cb[(size_t)row * D_DIM + lane];
  float s = v * v;
  #pragma unroll
  for (int m = 1; m < 64; m <<= 1) s += __shfl_xor(s, m);
  float inv = rsqrtf(s * (1.0f / 64.0f) + 1e-12f);
  cn[(size_t)row * D_DIM + lane] = v * inv;
}

// ---------------------------------------------------------------------------
// K2b: swizzle fp32 [8192 x 64] into 3-limb bf16 MFMA fragment layout.
// Fragment f = (g*2 + c)*3 + limb  (g = 16-row group, c = k-chunk of 32).
// Within fragment: lane l gets row g*16+(l&15), ks c*32+(l>>4)*8 .. +8.
// dst[f*512 + l*8 + j]. One wave per (g,c) pair; 256 blocks x 256 thr.
__global__ __launch_bounds__(256) void k_swizzle(
    const float* __restrict__ src, unsigned short* __restrict__ dst) {
  const int tid = threadIdx.x;
  const int w = tid >> 6, l = tid & 63;
  const int pair = blockIdx.x * 4 + w;      // 0..1023
  const int g = pair >> 1, c = pair & 1;
  const int row = g * 16 + (l & 15);
  const int kb = c * 32 + (l >> 4) * 8;
  const float* sp = src + (size_t)row * D_DIM + kb;
  float4 x0 = *(const float4*)sp, x1 = *(const float4*)(sp + 4);
  float xs[8] = {x0.x, x0.y, x0.z, x0.w, x1.x, x1.y, x1.z, x1.w};
  unsigned short hs[8], ms[8], ls[8];
  #pragma unroll
  for (int j = 0; j < 8; ++j) {
    float x = xs[j];
    unsigned short h = rne_bf16(x);
    float r1 = x - bf16_to_f(h);
    unsigned short m = rne_bf16(r1);
    float r2 = r1 - bf16_to_f(m);
    unsigned short lo = rne_bf16(r2);
    hs[j] = h; ms[j] = m; ls[j] = lo;
  }
  const int fbase = (g * 2 + c) * 3;
  unsigned short* d0 = dst + (size_t)(fbase + 0) * 512 + l * 8;
  unsigned short* d1 = dst + (size_t)(fbase + 1) * 512 + l * 8;
  unsigned short* d2 = dst + (size_t)(fbase + 2) * 512 + l * 8;
  #pragma unroll
  for (int j = 0; j < 8; ++j) { d0[j] = hs[j]; d1[j] = ms[j]; d2[j] = ls[j]; }
}

// ---------------------------------------------------------------------------
// K3 v3: MFMA argmax. Grid (128, 4): x = M-group (64 rows), y = code quarter
// (2048 codes). 4 waves/block, wave = one 16-row M-tile, sweeps all 2048
// codes (128 passes x 16 codes). LDS-free, barrier-free.
// S = zn.cn^T via 6-term 3-limb bf16 MFMA (fp32-class accuracy).
__global__ __launch_bounds__(256, 2) void k_argmax(
    const unsigned short* __restrict__ zn_sw,
    const unsigned short* __restrict__ cn_sw,
    float* __restrict__ pval, int* __restrict__ pidx) {
  const int tid = threadIdx.x;
  const int w = tid >> 6, l = tid & 63;
  const int mg = blockIdx.x;                // 0..127
  const int q = blockIdx.y;                 // 0..3
  const int gA = mg * 4 + w;                // A 16-row group
  const int gB0 = q * 128;                  // first B group of this quarter

  const bf16x8* Ab = (const bf16x8*)zn_sw;  // fragment = 64 bf16x8 units
  const bf16x8* Bb = (const bf16x8*)cn_sw;

  // A fragments resident: [chunk][limb]
  bf16x8 A[2][3];
  #pragma unroll
  for (int c = 0; c < 2; ++c)
    #pragma unroll
    for (int m = 0; m < 3; ++m)
      A[c][m] = Ab[(size_t)(((gA * 2 + c) * 3 + m)) * 64 + l];

  bf16x8 Bu[2][3], Bv[2][3];
  #pragma unroll
  for (int c = 0; c < 2; ++c)
    #pragma unroll
    for (int m = 0; m < 3; ++m)
      Bu[c][m] = Bb[(size_t)(((gB0 * 2 + c) * 3 + m)) * 64 + l];

  float bv[4] = {-1e30f, -1e30f, -1e30f, -1e30f};
  int bi[4] = {0, 0, 0, 0};
  int cand = q * 2048 + (l & 15);

  #define LOADB(dst, gB)                                                     \
    _Pragma("unroll")                                                        \
    for (int c = 0; c < 2; ++c)                                              \
      _Pragma("unroll")                                                      \
      for (int m = 0; m < 3; ++m)                                            \
        dst[c][m] = Bb[(size_t)((((gB) * 2 + c) * 3 + m)) * 64 + l];

  #define COMPUTE(B)                                                          \
    {                                                                         \
      f32x4 a0 = {0.f, 0.f, 0.f, 0.f}, a1 = {0.f, 0.f, 0.f, 0.f};             \
      a0 = __builtin_amdgcn_mfma_f32_16x16x32_bf16(A[0][0], B[0][0], a0, 0, 0, 0); \
      a1 = __builtin_amdgcn_mfma_f32_16x16x32_bf16(A[1][0], B[1][0], a1, 0, 0, 0); \
      a0 = __builtin_amdgcn_mfma_f32_16x16x32_bf16(A[0][0], B[0][1], a0, 0, 0, 0); \
      a1 = __builtin_amdgcn_mfma_f32_16x16x32_bf16(A[1][0], B[1][1], a1, 0, 0, 0); \
      a0 = __builtin_amdgcn_mfma_f32_16x16x32_bf16(A[0][1], B[0][0], a0, 0, 0, 0); \
      a1 = __builtin_amdgcn_mfma_f32_16x16x32_bf16(A[1][1], B[1][0], a1, 0, 0, 0); \
      a0 = __builtin_amdgcn_mfma_f32_16x16x32_bf16(A[0][0], B[0][2], a0, 0, 0, 0); \
      a1 = __builtin_amdgcn_mfma_f32_16x16x32_bf16(A[1][0], B[1][2], a1, 0, 0, 0); \
      a0 = __builtin_amdgcn_mfma_f32_16x16x32_bf16(A[0][2], B[0][0], a0, 0, 0, 0); \
      a1 = __builtin_amdgcn_mfma_f32_16x16x32_bf16(A[1][2], B[1][0], a1, 0, 0, 0); \
      a0 = __builtin_amdgcn_mfma_f32_16x16x32_bf16(A[0][1], B[0][1], a0, 0, 0, 0); \
      a1 = __builtin_amdgcn_mfma_f32_16x16x32_bf16(A[1][1], B[1][1], a1, 0, 0, 0); \
      _Pragma("unroll")                                                       \
      for (int r = 0; r < 4; ++r) {                                           \
        float d = a0[r] + a1[r];                                              \
        if (d > bv[r]) { bv[r] = d; bi[r] = cand; }                           \
      }                                                                       \
      cand += 16;                                                             \
    }

  for (int p = 0; p < 128; p += 2) {
    LOADB(Bv, gB0 + p + 1);
    COMPUTE(Bu);
    LOADB(Bu, gB0 + p + 2);   // p=126 over-reads one group into padded ws
    COMPUTE(Bv);
  }
  #undef LOADB
  #undef COMPUTE

  // reduce across the 16 column-slots (lanes l&15) for each row
  #pragma unroll
  for (int r = 0; r < 4; ++r) {
    float v = bv[r]; int ix = bi[r];
    #pragma unroll
    for (int m = 1; m < 16; m <<= 1) {
      float ov = __shfl_xor(v, m);
      int oi = __shfl_xor(ix, m);
      if (ov > v || (ov == v && oi < ix)) { v = ov; ix = oi; }
    }
    bv[r] = v; bi[r] = ix;
  }
  if ((l & 15) == 0) {
    // C/D layout: this lane's rows = (l>>4)*4 + r within the wave's M-tile
    int rowb = mg * 64 + w * 16 + (l >> 4) * 4;
    int off = q * N_ROWS + rowb;
    #pragma unroll
    for (int r = 0; r < 4; ++r) { pval[off + r] = bv[r]; pidx[off + r] = bi[r]; }
  }
}

// ---------------------------------------------------------------------------
// K3b: merge the four code-quarter partials (ascending q, strict > keeps
// the lowest index on ties -> argmin first-hit semantics).
__global__ __launch_bounds__(256) void k_merge(
    const float* __restrict__ pval, const int* __restrict__ pidx,
    int* __restrict__ idx_out, float* __restrict__ idx_f) {
  int row = blockIdx.x * 256 + threadIdx.x;
  float v = pval[row]; int ix = pidx[row];
  #pragma unroll
  for (int q = 1; q < 4; ++q) {
    float vq = pval[q * N_ROWS + row];
    int iq = pidx[q * N_ROWS + row];
    if (vq > v) { v = vq; ix = iq; }
  }
  idx_out[row] = ix;
  idx_f[row] = (float)ix;
}

// ---------------------------------------------------------------------------
// K4: out = cn[idx] @ W_out + b_out + loss partials  (unchanged)
__global__ __launch_bounds__(256) void k_out(
    const float* __restrict__ cn, const float* __restrict__ zn,
    const int* __restrict__ idx, const float* __restrict__ W_out,
    const float* __restrict__ b_out, float* __restrict__ out,
    float* __restrict__ loss_acc) {
  __shared__ float w_lds[128 * 66];
  __shared__ float cq_lds[32 * 68];
  const int tid = threadIdx.x;
  const int row0 = blockIdx.x * 32;
  const int rg = tid >> 5, cg = tid & 31;

  float lp = 0.0f;
  {
    int r = tid >> 3, j = tid & 7;
    int code = idx[row0 + r];
    const float* src = cn + (size_t)code * D_DIM + j * 8;
    const float* zsrc = zn + (size_t)(row0 + r) * D_DIM + j * 8;
    float4 a = *(const float4*)src, b = *(const float4*)(src + 4);
    float4 za = *(const float4*)zsrc, zb = *(const float4*)(zsrc + 4);
    float* dst = cq_lds + r * 68 + j * 8;
    *(float4*)dst = a; *(float4*)(dst + 4) = b;
    float dx = a.x - za.x, dy = a.y - za.y, dz = a.z - za.z, dw = a.w - za.w;
    lp = dx * dx + dy * dy + dz * dz + dw * dw;
    dx = b.x - zb.x; dy = b.y - zb.y; dz = b.z - zb.z; dw = b.w - zb.w;
    lp += dx * dx + dy * dy + dz * dz + dw * dw;
  }
  #pragma unroll
  for (int m = 1; m < 64; m <<= 1) lp += __shfl_xor(lp, m);
  if ((tid & 63) == 0) atomicAdd(loss_acc, lp);

  for (int q = 0; q < 4; ++q) {
    __syncthreads();
    {
      int m = tid & 31;
      int kb = tid >> 5;
      for (int p = 0; p < 8; ++p) {
        int k = p * 8 + kb;
        float4 wv = *(const float4*)(W_out + (size_t)k * F_DIM + q * 128 + m * 4);
        w_lds[(m * 4 + 0) * 66 + k] = wv.x;
        w_lds[(m * 4 + 1) * 66 + k] = wv.y;
        w_lds[(m * 4 + 2) * 66 + k] = wv.z;
        w_lds[(m * 4 + 3) * 66 + k] = wv.w;
      }
    }
    __syncthreads();
    float acc[4][4] = {};
    for (int k = 0; k < 64; k += 4) {
      float4 av[4];
      #pragma unroll
      for (int r = 0; r < 4; ++r)
        av[r] = *(const float4*)(cq_lds + (rg * 4 + r) * 68 + k);
      #pragma unroll
      for (int j = 0; j < 4; ++j) {
        const float* wp = w_lds + (cg + 32 * j) * 66 + k;
        float2 w0 = *(const float2*)wp, w1 = *(const float2*)(wp + 2);
        #pragma unroll
        for (int r = 0; r < 4; ++r)
          acc[r][j] += av[r].x * w0.x + av[r].y * w0.y + av[r].z * w1.x + av[r].w * w1.y;
      }
    }
    #pragma unroll
    for (int j = 0; j < 4; ++j) {
      int col = q * 128 + cg + 32 * j;
      float b = b_out[col];
      #pragma unroll
      for (int r = 0; r < 4; ++r) {
        int row = row0 + rg * 4 + r;
        out[(size_t)row * F_DIM + col] = acc[r][j] + b;
      }
    }
  }
}

// ---------------------------------------------------------------------------
__global__ void k_loss_final(const float* __restrict__ loss,
                             float* __restrict__ out) {
  out[0] = loss[0] * (1.25f / (float)(N_ROWS * D_DIM));
}

// ---------------------------------------------------------------------------
extern "C" void kernel_launch(void* const* d_in, const int* in_sizes, int n_in,
                              void* d_out, int out_size, void* d_ws, size_t ws_size,
                              hipStream_t stream) {
  const float* z        = (const float*)d_in[0];
  const float* W_in     = (const float*)d_in[1];
  const float* b_in     = (const float*)d_in[2];
  const float* codebook = (const float*)d_in[3];
  const float* W_out    = (const float*)d_in[4];
  const float* b_out    = (const float*)d_in[5];

  float* outp   = (float*)d_out;                      // Output 0: [8192 x 512]
  float* loss_f = outp + (size_t)N_ROWS * F_DIM;      // Output 1
  float* idx_f  = loss_f + 1;                         // Output 2

  // workspace layout (float units)
  float* wsf = (float*)d_ws;
  float* zn_ws = wsf;                                  // [0, 524288)
  float* cn_ws = wsf + 524288;                         // [524288, 1048576)
  float* loss_ws = wsf + 1048576;                      // 1
  int*   idx_ws  = (int*)(wsf + 1048592);              // 8192 ints
  unsigned short* zn_sw = (unsigned short*)(wsf + 1056784);  // 1.57M u16 = 786432 f
  unsigned short* cn_sw = (unsigned short*)(wsf + 1843216);  // 786432 f
  // 16 KB pad after cn_sw for prefetch over-read: [2629648, 2633744)
  float* pval_ws = wsf + 2633744;                      // 32768 f (4 x 8192)
  int*   pidx_ws = (int*)(wsf + 2666512);              // 32768 ints
  // total ~10.8 MB

  hipLaunchKernelGGL(k_init, dim3(1), dim3(1), 0, stream, loss_ws);
  hipLaunchKernelGGL(k_zn, dim3(N_ROWS / 32), dim3(256), 0, stream,
                     z, W_in, b_in, zn_ws);
  hipLaunchKernelGGL(k_cn, dim3(C_CODES / 4), dim3(256), 0, stream,
                     codebook, cn_ws);
  hipLaunchKernelGGL(k_swizzle, dim3(256), dim3(256), 0, stream, zn_ws, zn_sw);
  hipLaunchKernelGGL(k_swizzle, dim3(256), dim3(256), 0, stream, cn_ws, cn_sw);
  hipLaunchKernelGGL(k_argmax, dim3(128, 4), dim3(256), 0, stream,
                     zn_sw, cn_sw, pval_ws, pidx_ws);
  hipLaunchKernelGGL(k_merge, dim3(N_ROWS / 256), dim3(256), 0, stream,
                     pval_ws, pidx_ws, idx_ws, idx_f);
  hipLaunchKernelGGL(k_out, dim3(N_ROWS / 32), dim3(256), 0, stream,
                     cn_ws, zn_ws, idx_ws, W_out, b_out, outp, loss_ws);
  hipLaunchKernelGGL(k_loss_final, dim3(1), dim3(1), 0, stream,
                     loss_ws, loss_f);
}

// Round 8
// 174.781 us; speedup vs baseline: 2.6910x; 1.2745x over previous
//
#include <hip/hip_runtime.h>
#include <hip/hip_bf16.h>

// Problem constants
#define N_ROWS 8192
#define F_DIM  512
#define D_DIM  64
#define C_CODES 8192

typedef __attribute__((ext_vector_type(8))) short bf16x8;   // 8 bf16 = 4 VGPRs
typedef __attribute__((ext_vector_type(4))) float f32x4;

__device__ __forceinline__ unsigned short rne_bf16(float x) {
  unsigned u = __float_as_uint(x);
  return (unsigned short)((u + 0x7FFFu + ((u >> 16) & 1u)) >> 16);
}
__device__ __forceinline__ float bf16_to_f(unsigned short u) {
  return __uint_as_float(((unsigned)u) << 16);
}
// split 8 floats into 3 bf16 limbs (h+m+l reproduces x to ~2^-24 rel)
__device__ __forceinline__ void limb3(const float* xs, bf16x8& H, bf16x8& M, bf16x8& L) {
  #pragma unroll
  for (int j = 0; j < 8; ++j) {
    float x = xs[j];
    unsigned short h = rne_bf16(x);
    float r1 = x - bf16_to_f(h);
    unsigned short m = rne_bf16(r1);
    float r2 = r1 - bf16_to_f(m);
    unsigned short lo = rne_bf16(r2);
    H[j] = (short)h; M[j] = (short)m; L[j] = (short)lo;
  }
}

// ---------------------------------------------------------------------------
__global__ void k_init(float* __restrict__ loss) { loss[0] = 0.0f; }

// ---------------------------------------------------------------------------
// Swizzle W_in [512][64] -> 3-limb frags: ((kc*4+cg)*3+m)*512 + l*8 + j
// holds W_in[kc*32+(l>>4)*8+j][cg*16+(l&15)].  64 wave-tasks.
__global__ __launch_bounds__(256) void k_swz_win(
    const float* __restrict__ W, unsigned short* __restrict__ dst) {
  const int tid = threadIdx.x, w = tid >> 6, l = tid & 63;
  const int task = blockIdx.x * 4 + w;      // 0..63
  const int kc = task >> 2, cg = task & 3;
  const int lo = l & 15, hi = l >> 4;
  float xs[8];
  #pragma unroll
  for (int j = 0; j < 8; ++j)
    xs[j] = W[(size_t)(kc * 32 + hi * 8 + j) * D_DIM + cg * 16 + lo];
  bf16x8 H, M, L;
  limb3(xs, H, M, L);
  const int fb = (kc * 4 + cg) * 3;
  unsigned short* d0 = dst + (size_t)(fb + 0) * 512 + l * 8;
  unsigned short* d1 = dst + (size_t)(fb + 1) * 512 + l * 8;
  unsigned short* d2 = dst + (size_t)(fb + 2) * 512 + l * 8;
  #pragma unroll
  for (int j = 0; j < 8; ++j) { d0[j] = (unsigned short)H[j]; d1[j] = (unsigned short)M[j]; d2[j] = (unsigned short)L[j]; }
}

// Swizzle W_out [64][512] -> frags ((cg*2+c)*3+m)*512 + l*8 + j holding
// W_out[c*32+(l>>4)*8+j][cg*16+(l&15)].  64 wave-tasks.
__global__ __launch_bounds__(256) void k_swz_wout(
    const float* __restrict__ W, unsigned short* __restrict__ dst) {
  const int tid = threadIdx.x, w = tid >> 6, l = tid & 63;
  const int task = blockIdx.x * 4 + w;      // 0..63
  const int cg = task >> 1, c = task & 1;
  const int lo = l & 15, hi = l >> 4;
  float xs[8];
  #pragma unroll
  for (int j = 0; j < 8; ++j)
    xs[j] = W[(size_t)(c * 32 + hi * 8 + j) * F_DIM + cg * 16 + lo];
  bf16x8 H, M, L;
  limb3(xs, H, M, L);
  const int fb = (cg * 2 + c) * 3;
  unsigned short* d0 = dst + (size_t)(fb + 0) * 512 + l * 8;
  unsigned short* d1 = dst + (size_t)(fb + 1) * 512 + l * 8;
  unsigned short* d2 = dst + (size_t)(fb + 2) * 512 + l * 8;
  #pragma unroll
  for (int j = 0; j < 8; ++j) { d0[j] = (unsigned short)H[j]; d1[j] = (unsigned short)M[j]; d2[j] = (unsigned short)L[j]; }
}

// ---------------------------------------------------------------------------
// K1 v2 (MFMA): zn = normalise(z @ W_in + b_in). Wave = 16 rows, K=512 in
// 16 chunks of 32; A (z) limb-split in-reg, B = w_in_sw streamed from L2.
// 128 blocks x 4 waves. No LDS.
__global__ __launch_bounds__(256) void k_zn(
    const float* __restrict__ z, const unsigned short* __restrict__ w_in_sw,
    const float* __restrict__ b_in, float* __restrict__ zn) {
  const int tid = threadIdx.x, w = tid >> 6, l = tid & 63;
  const int lo = l & 15, hi = l >> 4;
  const int r0 = (blockIdx.x * 4 + w) * 16;
  const bf16x8* B = (const bf16x8*)w_in_sw;   // frag = 64 bf16x8 units

  f32x4 acc0 = {0.f,0.f,0.f,0.f}, acc1 = {0.f,0.f,0.f,0.f};
  f32x4 acc2 = {0.f,0.f,0.f,0.f}, acc3 = {0.f,0.f,0.f,0.f};

  for (int kc = 0; kc < 16; ++kc) {
    const float* zp = z + (size_t)(r0 + lo) * F_DIM + kc * 32 + hi * 8;
    float4 x0 = *(const float4*)zp, x1 = *(const float4*)(zp + 4);
    float xs[8] = {x0.x, x0.y, x0.z, x0.w, x1.x, x1.y, x1.z, x1.w};
    bf16x8 Ah, Am, Al;
    limb3(xs, Ah, Am, Al);
    const bf16x8* Bc = B + (size_t)kc * 12 * 64 + l;   // 12 frags per chunk
    #pragma unroll
    for (int cg = 0; cg < 4; ++cg) {
      bf16x8 Bh = Bc[(cg * 3 + 0) * 64];
      bf16x8 Bm = Bc[(cg * 3 + 1) * 64];
      bf16x8 Bl = Bc[(cg * 3 + 2) * 64];
      f32x4* a = (cg == 0) ? &acc0 : (cg == 1) ? &acc1 : (cg == 2) ? &acc2 : &acc3;
      f32x4 t = *a;
      t = __builtin_amdgcn_mfma_f32_16x16x32_bf16(Ah, Bh, t, 0, 0, 0);
      t = __builtin_amdgcn_mfma_f32_16x16x32_bf16(Ah, Bm, t, 0, 0, 0);
      t = __builtin_amdgcn_mfma_f32_16x16x32_bf16(Am, Bh, t, 0, 0, 0);
      t = __builtin_amdgcn_mfma_f32_16x16x32_bf16(Ah, Bl, t, 0, 0, 0);
      t = __builtin_amdgcn_mfma_f32_16x16x32_bf16(Al, Bh, t, 0, 0, 0);
      t = __builtin_amdgcn_mfma_f32_16x16x32_bf16(Am, Bm, t, 0, 0, 0);
      *a = t;
    }
  }

  float bias[4];
  #pragma unroll
  for (int cg = 0; cg < 4; ++cg) bias[cg] = b_in[cg * 16 + lo];

  f32x4* accs[4] = {&acc0, &acc1, &acc2, &acc3};
  #pragma unroll
  for (int r = 0; r < 4; ++r) {
    float v[4], s = 0.0f;
    #pragma unroll
    for (int cg = 0; cg < 4; ++cg) {
      v[cg] = (*accs[cg])[r] + bias[cg];
      s += v[cg] * v[cg];
    }
    s += __shfl_xor(s, 1);
    s += __shfl_xor(s, 2);
    s += __shfl_xor(s, 4);
    s += __shfl_xor(s, 8);
    float inv = rsqrtf(s * (1.0f / 64.0f) + 1e-12f);
    int row = r0 + hi * 4 + r;
    #pragma unroll
    for (int cg = 0; cg < 4; ++cg)
      zn[(size_t)row * D_DIM + cg * 16 + lo] = v[cg] * inv;
  }
}

// ---------------------------------------------------------------------------
// K2: cn = normalise(codebook)  (unchanged)
__global__ __launch_bounds__(256) void k_cn(
    const float* __restrict__ cb, float* __restrict__ cn) {
  int row = blockIdx.x * 4 + (threadIdx.x >> 6);
  int lane = threadIdx.x & 63;
  float v = cb[(size_t)row * D_DIM + lane];
  float s = v * v;
  #pragma unroll
  for (int m = 1; m < 64; m <<= 1) s += __shfl_xor(s, m);
  float inv = rsqrtf(s * (1.0f / 64.0f) + 1e-12f);
  cn[(size_t)row * D_DIM + lane] = v * inv;
}

// ---------------------------------------------------------------------------
// K2b: swizzle fp32 [8192 x 64] -> 3-limb bf16 A/B fragments (unchanged R7)
__global__ __launch_bounds__(256) void k_swizzle(
    const float* __restrict__ src, unsigned short* __restrict__ dst) {
  const int tid = threadIdx.x;
  const int w = tid >> 6, l = tid & 63;
  const int pair = blockIdx.x * 4 + w;      // 0..1023
  const int g = pair >> 1, c = pair & 1;
  const int row = g * 16 + (l & 15);
  const int kb = c * 32 + (l >> 4) * 8;
  const float* sp = src + (size_t)row * D_DIM + kb;
  float4 x0 = *(const float4*)sp, x1 = *(const float4*)(sp + 4);
  float xs[8] = {x0.x, x0.y, x0.z, x0.w, x1.x, x1.y, x1.z, x1.w};
  bf16x8 H, M, L;
  limb3(xs, H, M, L);
  const int fbase = (g * 2 + c) * 3;
  unsigned short* d0 = dst + (size_t)(fbase + 0) * 512 + l * 8;
  unsigned short* d1 = dst + (size_t)(fbase + 1) * 512 + l * 8;
  unsigned short* d2 = dst + (size_t)(fbase + 2) * 512 + l * 8;
  #pragma unroll
  for (int j = 0; j < 8; ++j) { d0[j] = (unsigned short)H[j]; d1[j] = (unsigned short)M[j]; d2[j] = (unsigned short)L[j]; }
}

// ---------------------------------------------------------------------------
// K3 v4: MFMA argmax, 32 rows/wave (2 A-groups -> 24 MFMA per 6-frag B load).
// Grid (64, 8): x = M-group (128 rows/block), y = code eighth (1024 codes,
// 64 passes). LDS-free, barrier-free, register ping-pong B.
__global__ __launch_bounds__(256, 2) void k_argmax(
    const unsigned short* __restrict__ zn_sw,
    const unsigned short* __restrict__ cn_sw,
    float* __restrict__ pval, int* __restrict__ pidx) {
  const int tid = threadIdx.x;
  const int w = tid >> 6, l = tid & 63;
  const int lo = l & 15, hi = l >> 4;
  const int gA0 = (blockIdx.x * 4 + w) * 2;   // 0..510 (16-row groups)
  const int gB0 = blockIdx.y * 64;            // B group base
  const bf16x8* Ab = (const bf16x8*)zn_sw;
  const bf16x8* Bb = (const bf16x8*)cn_sw;

  bf16x8 A0[2][3], A1[2][3];
  #pragma unroll
  for (int c = 0; c < 2; ++c)
    #pragma unroll
    for (int m = 0; m < 3; ++m) {
      A0[c][m] = Ab[(size_t)((gA0 * 2 + c) * 3 + m) * 64 + l];
      A1[c][m] = Ab[(size_t)(((gA0 + 1) * 2 + c) * 3 + m) * 64 + l];
    }

  bf16x8 Bu[2][3], Bv[2][3];
  #pragma unroll
  for (int c = 0; c < 2; ++c)
    #pragma unroll
    for (int m = 0; m < 3; ++m)
      Bu[c][m] = Bb[(size_t)((gB0 * 2 + c) * 3 + m) * 64 + l];

  float bv[8];
  int bi[8];
  #pragma unroll
  for (int i = 0; i < 8; ++i) { bv[i] = -1e30f; bi[i] = 0; }
  int cand = blockIdx.y * 1024 + lo;

  #define LOADB(dst, gB)                                                     \
    _Pragma("unroll")                                                        \
    for (int c = 0; c < 2; ++c)                                              \
      _Pragma("unroll")                                                      \
      for (int m = 0; m < 3; ++m)                                            \
        dst[c][m] = Bb[(size_t)(((gB) * 2 + c) * 3 + m) * 64 + l];

  #define COMPUTE(B)                                                          \
    {                                                                         \
      f32x4 a0 = {0.f,0.f,0.f,0.f}, a1 = {0.f,0.f,0.f,0.f};                   \
      f32x4 a2 = {0.f,0.f,0.f,0.f}, a3 = {0.f,0.f,0.f,0.f};                   \
      a0 = __builtin_amdgcn_mfma_f32_16x16x32_bf16(A0[0][0], B[0][0], a0, 0,0,0); \
      a1 = __builtin_amdgcn_mfma_f32_16x16x32_bf16(A0[1][0], B[1][0], a1, 0,0,0); \
      a2 = __builtin_amdgcn_mfma_f32_16x16x32_bf16(A1[0][0], B[0][0], a2, 0,0,0); \
      a3 = __builtin_amdgcn_mfma_f32_16x16x32_bf16(A1[1][0], B[1][0], a3, 0,0,0); \
      a0 = __builtin_amdgcn_mfma_f32_16x16x32_bf16(A0[0][0], B[0][1], a0, 0,0,0); \
      a1 = __builtin_amdgcn_mfma_f32_16x16x32_bf16(A0[1][0], B[1][1], a1, 0,0,0); \
      a2 = __builtin_amdgcn_mfma_f32_16x16x32_bf16(A1[0][0], B[0][1], a2, 0,0,0); \
      a3 = __builtin_amdgcn_mfma_f32_16x16x32_bf16(A1[1][0], B[1][1], a3, 0,0,0); \
      a0 = __builtin_amdgcn_mfma_f32_16x16x32_bf16(A0[0][1], B[0][0], a0, 0,0,0); \
      a1 = __builtin_amdgcn_mfma_f32_16x16x32_bf16(A0[1][1], B[1][0], a1, 0,0,0); \
      a2 = __builtin_amdgcn_mfma_f32_16x16x32_bf16(A1[0][1], B[0][0], a2, 0,0,0); \
      a3 = __builtin_amdgcn_mfma_f32_16x16x32_bf16(A1[1][1], B[1][0], a3, 0,0,0); \
      a0 = __builtin_amdgcn_mfma_f32_16x16x32_bf16(A0[0][0], B[0][2], a0, 0,0,0); \
      a1 = __builtin_amdgcn_mfma_f32_16x16x32_bf16(A0[1][0], B[1][2], a1, 0,0,0); \
      a2 = __builtin_amdgcn_mfma_f32_16x16x32_bf16(A1[0][0], B[0][2], a2, 0,0,0); \
      a3 = __builtin_amdgcn_mfma_f32_16x16x32_bf16(A1[1][0], B[1][2], a3, 0,0,0); \
      a0 = __builtin_amdgcn_mfma_f32_16x16x32_bf16(A0[0][2], B[0][0], a0, 0,0,0); \
      a1 = __builtin_amdgcn_mfma_f32_16x16x32_bf16(A0[1][2], B[1][0], a1, 0,0,0); \
      a2 = __builtin_amdgcn_mfma_f32_16x16x32_bf16(A1[0][2], B[0][0], a2, 0,0,0); \
      a3 = __builtin_amdgcn_mfma_f32_16x16x32_bf16(A1[1][2], B[1][0], a3, 0,0,0); \
      a0 = __builtin_amdgcn_mfma_f32_16x16x32_bf16(A0[0][1], B[0][1], a0, 0,0,0); \
      a1 = __builtin_amdgcn_mfma_f32_16x16x32_bf16(A0[1][1], B[1][1], a1, 0,0,0); \
      a2 = __builtin_amdgcn_mfma_f32_16x16x32_bf16(A1[0][1], B[0][1], a2, 0,0,0); \
      a3 = __builtin_amdgcn_mfma_f32_16x16x32_bf16(A1[1][1], B[1][1], a3, 0,0,0); \
      _Pragma("unroll")                                                       \
      for (int r = 0; r < 4; ++r) {                                           \
        float d0 = a0[r] + a1[r];                                             \
        if (d0 > bv[r]) { bv[r] = d0; bi[r] = cand; }                         \
        float d1 = a2[r] + a3[r];                                             \
        if (d1 > bv[4 + r]) { bv[4 + r] = d1; bi[4 + r] = cand; }             \
      }                                                                       \
      cand += 16;                                                             \
    }

  for (int p = 0; p < 64; p += 2) {
    LOADB(Bv, gB0 + p + 1);
    COMPUTE(Bu);
    LOADB(Bu, gB0 + p + 2);   // last iter over-reads one group into pad
    COMPUTE(Bv);
  }
  #undef LOADB
  #undef COMPUTE

  #pragma unroll
  for (int i = 0; i < 8; ++i) {
    float v = bv[i]; int ix = bi[i];
    #pragma unroll
    for (int m = 1; m < 16; m <<= 1) {
      float ov = __shfl_xor(v, m);
      int oi = __shfl_xor(ix, m);
      if (ov > v || (ov == v && oi < ix)) { v = ov; ix = oi; }
    }
    bv[i] = v; bi[i] = ix;
  }
  if (lo == 0) {
    int off = blockIdx.y * N_ROWS;
    int base0 = gA0 * 16 + hi * 4;
    int base1 = (gA0 + 1) * 16 + hi * 4;
    #pragma unroll
    for (int r = 0; r < 4; ++r) {
      pval[off + base0 + r] = bv[r];     pidx[off + base0 + r] = bi[r];
      pval[off + base1 + r] = bv[4 + r]; pidx[off + base1 + r] = bi[4 + r];
    }
  }
}

// ---------------------------------------------------------------------------
// K3b: merge 8 code-eighth partials (ascending q + strict > => lowest index
// on ties, matching argmin first-hit).
__global__ __launch_bounds__(256) void k_merge(
    const float* __restrict__ pval, const int* __restrict__ pidx,
    int* __restrict__ idx_out, float* __restrict__ idx_f) {
  int row = blockIdx.x * 256 + threadIdx.x;
  float v = pval[row]; int ix = pidx[row];
  #pragma unroll
  for (int q = 1; q < 8; ++q) {
    float vq = pval[q * N_ROWS + row];
    int iq = pidx[q * N_ROWS + row];
    if (vq > v) { v = vq; ix = iq; }
  }
  idx_out[row] = ix;
  idx_f[row] = (float)ix;
}

// ---------------------------------------------------------------------------
// K4 v2 (MFMA): out = cn[idx] @ W_out + b_out + fused loss partials.
// Wave = 16 gathered rows; A limb-split in-reg from gathered cn; B = w_out_sw.
// 128 blocks x 4 waves. No LDS.
__global__ __launch_bounds__(256) void k_out(
    const float* __restrict__ cn, const float* __restrict__ zn,
    const int* __restrict__ idx, const unsigned short* __restrict__ w_out_sw,
    const float* __restrict__ b_out, float* __restrict__ out,
    float* __restrict__ loss_acc) {
  const int tid = threadIdx.x, w = tid >> 6, l = tid & 63;
  const int lo = l & 15, hi = l >> 4;
  const int r0 = (blockIdx.x * 4 + w) * 16;
  const int code = idx[r0 + lo];

  bf16x8 A[2][3];
  float lp = 0.0f;
  #pragma unroll
  for (int c = 0; c < 2; ++c) {
    const float* cp = cn + (size_t)code * D_DIM + c * 32 + hi * 8;
    const float* zp = zn + (size_t)(r0 + lo) * D_DIM + c * 32 + hi * 8;
    float4 c0 = *(const float4*)cp, c1 = *(const float4*)(cp + 4);
    float4 z0 = *(const float4*)zp, z1 = *(const float4*)(zp + 4);
    float xs[8] = {c0.x, c0.y, c0.z, c0.w, c1.x, c1.y, c1.z, c1.w};
    float zs[8] = {z0.x, z0.y, z0.z, z0.w, z1.x, z1.y, z1.z, z1.w};
    limb3(xs, A[c][0], A[c][1], A[c][2]);
    #pragma unroll
    for (int j = 0; j < 8; ++j) { float d = xs[j] - zs[j]; lp += d * d; }
  }
  #pragma unroll
  for (int m = 1; m < 64; m <<= 1) lp += __shfl_xor(lp, m);
  if (l == 0) atomicAdd(loss_acc, lp);

  const bf16x8* B = (const bf16x8*)w_out_sw;
  for (int cg = 0; cg < 32; ++cg) {
    bf16x8 Bf[2][3];
    #pragma unroll
    for (int c = 0; c < 2; ++c)
      #pragma unroll
      for (int m = 0; m < 3; ++m)
        Bf[c][m] = B[(size_t)((cg * 2 + c) * 3 + m) * 64 + l];
    f32x4 a0 = {0.f,0.f,0.f,0.f}, a1 = {0.f,0.f,0.f,0.f};
    a0 = __builtin_amdgcn_mfma_f32_16x16x32_bf16(A[0][0], Bf[0][0], a0, 0,0,0);
    a1 = __builtin_amdgcn_mfma_f32_16x16x32_bf16(A[1][0], Bf[1][0], a1, 0,0,0);
    a0 = __builtin_amdgcn_mfma_f32_16x16x32_bf16(A[0][0], Bf[0][1], a0, 0,0,0);
    a1 = __builtin_amdgcn_mfma_f32_16x16x32_bf16(A[1][0], Bf[1][1], a1, 0,0,0);
    a0 = __builtin_amdgcn_mfma_f32_16x16x32_bf16(A[0][1], Bf[0][0], a0, 0,0,0);
    a1 = __builtin_amdgcn_mfma_f32_16x16x32_bf16(A[1][1], Bf[1][0], a1, 0,0,0);
    a0 = __builtin_amdgcn_mfma_f32_16x16x32_bf16(A[0][0], Bf[0][2], a0, 0,0,0);
    a1 = __builtin_amdgcn_mfma_f32_16x16x32_bf16(A[1][0], Bf[1][2], a1, 0,0,0);
    a0 = __builtin_amdgcn_mfma_f32_16x16x32_bf16(A[0][2], Bf[0][0], a0, 0,0,0);
    a1 = __builtin_amdgcn_mfma_f32_16x16x32_bf16(A[1][2], Bf[1][0], a1, 0,0,0);
    a0 = __builtin_amdgcn_mfma_f32_16x16x32_bf16(A[0][1], Bf[0][1], a0, 0,0,0);
    a1 = __builtin_amdgcn_mfma_f32_16x16x32_bf16(A[1][1], Bf[1][1], a1, 0,0,0);
    float bb = b_out[cg * 16 + lo];
    #pragma unroll
    for (int r = 0; r < 4; ++r) {
      int row = r0 + hi * 4 + r;
      out[(size_t)row * F_DIM + cg * 16 + lo] = a0[r] + a1[r] + bb;
    }
  }
}

// ---------------------------------------------------------------------------
__global__ void k_loss_final(const float* __restrict__ loss,
                             float* __restrict__ out) {
  out[0] = loss[0] * (1.25f / (float)(N_ROWS * D_DIM));
}

// ---------------------------------------------------------------------------
extern "C" void kernel_launch(void* const* d_in, const int* in_sizes, int n_in,
                              void* d_out, int out_size, void* d_ws, size_t ws_size,
                              hipStream_t stream) {
  const float* z        = (const float*)d_in[0];
  const float* W_in     = (const float*)d_in[1];
  const float* b_in     = (const float*)d_in[2];
  const float* codebook = (const float*)d_in[3];
  const float* W_out    = (const float*)d_in[4];
  const float* b_out    = (const float*)d_in[5];

  float* outp   = (float*)d_out;                      // Output 0: [8192 x 512]
  float* loss_f = outp + (size_t)N_ROWS * F_DIM;      // Output 1
  float* idx_f  = loss_f + 1;                         // Output 2

  // workspace layout (float units)
  float* wsf = (float*)d_ws;
  float* zn_ws = wsf;                                        // [0, 524288)
  float* cn_ws = wsf + 524288;                               // [524288, 1048576)
  float* loss_ws = wsf + 1048576;                            // 1
  int*   idx_ws  = (int*)(wsf + 1048592);                    // 8192 ints
  unsigned short* zn_sw   = (unsigned short*)(wsf + 1056784); // 786432 f
  unsigned short* cn_sw   = (unsigned short*)(wsf + 1843216); // 786432 f
  // pad 4096 f after cn_sw for argmax prefetch over-read
  unsigned short* win_sw  = (unsigned short*)(wsf + 2633744); // 49152 f
  unsigned short* wout_sw = (unsigned short*)(wsf + 2682896); // 49152 f
  float* pval_ws = wsf + 2732048;                            // 65536 f (8 x 8192)
  int*   pidx_ws = (int*)(wsf + 2797584);                    // 65536 ints
  // total ends 2863120 floats ~ 11.5 MB

  hipLaunchKernelGGL(k_init, dim3(1), dim3(1), 0, stream, loss_ws);
  hipLaunchKernelGGL(k_swz_win, dim3(16), dim3(256), 0, stream, W_in, win_sw);
  hipLaunchKernelGGL(k_swz_wout, dim3(16), dim3(256), 0, stream, W_out, wout_sw);
  hipLaunchKernelGGL(k_cn, dim3(C_CODES / 4), dim3(256), 0, stream,
                     codebook, cn_ws);
  hipLaunchKernelGGL(k_zn, dim3(128), dim3(256), 0, stream,
                     z, win_sw, b_in, zn_ws);
  hipLaunchKernelGGL(k_swizzle, dim3(256), dim3(256), 0, stream, zn_ws, zn_sw);
  hipLaunchKernelGGL(k_swizzle, dim3(256), dim3(256), 0, stream, cn_ws, cn_sw);
  hipLaunchKernelGGL(k_argmax, dim3(64, 8), dim3(256), 0, stream,
                     zn_sw, cn_sw, pval_ws, pidx_ws);
  hipLaunchKernelGGL(k_merge, dim3(N_ROWS / 256), dim3(256), 0, stream,
                     pval_ws, pidx_ws, idx_ws, idx_f);
  hipLaunchKernelGGL(k_out, dim3(128), dim3(256), 0, stream,
                     cn_ws, zn_ws, idx_ws, wout_sw, b_out, outp, loss_ws);
  hipLaunchKernelGGL(k_loss_final, dim3(1), dim3(1), 0, stream,
                     loss_ws, loss_f);
}

// Round 9
// 154.790 us; speedup vs baseline: 3.0386x; 1.1291x over previous
//
#include <hip/hip_runtime.h>
#include <hip/hip_bf16.h>

// Problem constants
#define N_ROWS 8192
#define F_DIM  512
#define D_DIM  64
#define C_CODES 8192

typedef __attribute__((ext_vector_type(8))) short bf16x8;   // 8 bf16 = 4 VGPRs
typedef __attribute__((ext_vector_type(4))) float f32x4;

__device__ __forceinline__ unsigned short rne_bf16(float x) {
  unsigned u = __float_as_uint(x);
  return (unsigned short)((u + 0x7FFFu + ((u >> 16) & 1u)) >> 16);
}
__device__ __forceinline__ float bf16_to_f(unsigned short u) {
  return __uint_as_float(((unsigned)u) << 16);
}
// split 8 floats into 3 bf16 limbs (h+m+l reproduces x to ~2^-24 rel)
__device__ __forceinline__ void limb3(const float* xs, bf16x8& H, bf16x8& M, bf16x8& L) {
  #pragma unroll
  for (int j = 0; j < 8; ++j) {
    float x = xs[j];
    unsigned short h = rne_bf16(x);
    float r1 = x - bf16_to_f(h);
    unsigned short m = rne_bf16(r1);
    float r2 = r1 - bf16_to_f(m);
    unsigned short lo = rne_bf16(r2);
    H[j] = (short)h; M[j] = (short)m; L[j] = (short)lo;
  }
}

// ---------------------------------------------------------------------------
// Swizzle W_in [512][64] -> 3-limb frags: ((kc*4+cg)*3+m)*512 + l*8 + j
// holds W_in[kc*32+(l>>4)*8+j][cg*16+(l&15)].
__global__ __launch_bounds__(256) void k_swz_win(
    const float* __restrict__ W, unsigned short* __restrict__ dst) {
  const int tid = threadIdx.x, w = tid >> 6, l = tid & 63;
  const int task = blockIdx.x * 4 + w;      // 0..63
  const int kc = task >> 2, cg = task & 3;
  const int lo = l & 15, hi = l >> 4;
  float xs[8];
  #pragma unroll
  for (int j = 0; j < 8; ++j)
    xs[j] = W[(size_t)(kc * 32 + hi * 8 + j) * D_DIM + cg * 16 + lo];
  bf16x8 H, M, L;
  limb3(xs, H, M, L);
  const int fb = (kc * 4 + cg) * 3;
  unsigned short* d0 = dst + (size_t)(fb + 0) * 512 + l * 8;
  unsigned short* d1 = dst + (size_t)(fb + 1) * 512 + l * 8;
  unsigned short* d2 = dst + (size_t)(fb + 2) * 512 + l * 8;
  #pragma unroll
  for (int j = 0; j < 8; ++j) { d0[j] = (unsigned short)H[j]; d1[j] = (unsigned short)M[j]; d2[j] = (unsigned short)L[j]; }
}

// Swizzle W_out [64][512] -> frags ((cg*2+c)*3+m)*512 + l*8 + j holding
// W_out[c*32+(l>>4)*8+j][cg*16+(l&15)].
__global__ __launch_bounds__(256) void k_swz_wout(
    const float* __restrict__ W, unsigned short* __restrict__ dst) {
  const int tid = threadIdx.x, w = tid >> 6, l = tid & 63;
  const int task = blockIdx.x * 4 + w;      // 0..63
  const int cg = task >> 1, c = task & 1;
  const int lo = l & 15, hi = l >> 4;
  float xs[8];
  #pragma unroll
  for (int j = 0; j < 8; ++j)
    xs[j] = W[(size_t)(c * 32 + hi * 8 + j) * F_DIM + cg * 16 + lo];
  bf16x8 H, M, L;
  limb3(xs, H, M, L);
  const int fb = (cg * 2 + c) * 3;
  unsigned short* d0 = dst + (size_t)(fb + 0) * 512 + l * 8;
  unsigned short* d1 = dst + (size_t)(fb + 1) * 512 + l * 8;
  unsigned short* d2 = dst + (size_t)(fb + 2) * 512 + l * 8;
  #pragma unroll
  for (int j = 0; j < 8; ++j) { d0[j] = (unsigned short)H[j]; d1[j] = (unsigned short)M[j]; d2[j] = (unsigned short)L[j]; }
}

// ---------------------------------------------------------------------------
// K2 v2: cn = normalise(codebook) emitting BOTH fp32 rows and 3-limb frags
// directly (wave = 16 codes; lane l: code = g*16+(l&15), ks hi*8.. per chunk).
__global__ __launch_bounds__(256) void k_cn(
    const float* __restrict__ cb, float* __restrict__ cn,
    unsigned short* __restrict__ cn_sw) {
  const int tid = threadIdx.x, w = tid >> 6, l = tid & 63;
  const int g = blockIdx.x * 4 + w;         // 16-code group, 0..511
  const int lo = l & 15, hi = l >> 4;
  const int code = g * 16 + lo;

  float xs[2][8];
  float s = 0.0f;
  #pragma unroll
  for (int c = 0; c < 2; ++c) {
    const float* sp = cb + (size_t)code * D_DIM + c * 32 + hi * 8;
    float4 a = *(const float4*)sp, b = *(const float4*)(sp + 4);
    xs[c][0]=a.x; xs[c][1]=a.y; xs[c][2]=a.z; xs[c][3]=a.w;
    xs[c][4]=b.x; xs[c][5]=b.y; xs[c][6]=b.z; xs[c][7]=b.w;
    #pragma unroll
    for (int j = 0; j < 8; ++j) s += xs[c][j] * xs[c][j];
  }
  s += __shfl_xor(s, 16);
  s += __shfl_xor(s, 32);
  float inv = rsqrtf(s * (1.0f / 64.0f) + 1e-12f);

  #pragma unroll
  for (int c = 0; c < 2; ++c) {
    #pragma unroll
    for (int j = 0; j < 8; ++j) xs[c][j] *= inv;
    // fp32 store
    float* dp = cn + (size_t)code * D_DIM + c * 32 + hi * 8;
    *(float4*)dp = make_float4(xs[c][0], xs[c][1], xs[c][2], xs[c][3]);
    *(float4*)(dp + 4) = make_float4(xs[c][4], xs[c][5], xs[c][6], xs[c][7]);
    // frag store
    bf16x8 H, M, L;
    limb3(xs[c], H, M, L);
    const int fb = (g * 2 + c) * 3;
    unsigned short* d0 = cn_sw + (size_t)(fb + 0) * 512 + l * 8;
    unsigned short* d1 = cn_sw + (size_t)(fb + 1) * 512 + l * 8;
    unsigned short* d2 = cn_sw + (size_t)(fb + 2) * 512 + l * 8;
    #pragma unroll
    for (int j = 0; j < 8; ++j) { d0[j] = (unsigned short)H[j]; d1[j] = (unsigned short)M[j]; d2[j] = (unsigned short)L[j]; }
  }
}

// ---------------------------------------------------------------------------
// K1 v3 (MFMA, fused swizzle): zn = normalise(z @ W_in + b_in), emits fp32 +
// frags. 512 blocks x 1 wave (all CUs), ping-pong B prefetch, LDS transpose.
__global__ __launch_bounds__(64) void k_zn(
    const float* __restrict__ z, const unsigned short* __restrict__ w_in_sw,
    const float* __restrict__ b_in, float* __restrict__ zn,
    unsigned short* __restrict__ zn_sw) {
  __shared__ float t_lds[16 * 65];
  const int l = threadIdx.x;
  const int lo = l & 15, hi = l >> 4;
  const int g = blockIdx.x;                 // 16-row group
  const int r0 = g * 16;
  const bf16x8* Bptr = (const bf16x8*)w_in_sw;
  const float* zbase = z + (size_t)(r0 + lo) * F_DIM + hi * 8;

  f32x4 acc[4];
  #pragma unroll
  for (int cg = 0; cg < 4; ++cg) acc[cg] = (f32x4){0.f, 0.f, 0.f, 0.f};

  bf16x8 Bu[12], Bv[12];
  #pragma unroll
  for (int i = 0; i < 12; ++i) Bu[i] = Bptr[(size_t)i * 64 + l];
  float4 za = *(const float4*)zbase;
  float4 zb = *(const float4*)(zbase + 4);

  #define ZSTEP(BCUR, BNXT, KC)                                               \
    {                                                                         \
      int kn = ((KC) < 15) ? (KC) + 1 : 15;                                   \
      float4 na = *(const float4*)(zbase + kn * 32);                          \
      float4 nb = *(const float4*)(zbase + kn * 32 + 4);                      \
      _Pragma("unroll")                                                       \
      for (int i = 0; i < 12; ++i)                                            \
        BNXT[i] = Bptr[((size_t)kn * 12 + i) * 64 + l];                       \
      float xs[8] = {za.x, za.y, za.z, za.w, zb.x, zb.y, zb.z, zb.w};         \
      bf16x8 Ah, Am, Al;                                                      \
      limb3(xs, Ah, Am, Al);                                                  \
      _Pragma("unroll")                                                       \
      for (int cg = 0; cg < 4; ++cg) {                                        \
        f32x4 t = acc[cg];                                                    \
        t = __builtin_amdgcn_mfma_f32_16x16x32_bf16(Ah, BCUR[cg*3+0], t, 0,0,0); \
        t = __builtin_amdgcn_mfma_f32_16x16x32_bf16(Ah, BCUR[cg*3+1], t, 0,0,0); \
        t = __builtin_amdgcn_mfma_f32_16x16x32_bf16(Am, BCUR[cg*3+0], t, 0,0,0); \
        t = __builtin_amdgcn_mfma_f32_16x16x32_bf16(Ah, BCUR[cg*3+2], t, 0,0,0); \
        t = __builtin_amdgcn_mfma_f32_16x16x32_bf16(Al, BCUR[cg*3+0], t, 0,0,0); \
        t = __builtin_amdgcn_mfma_f32_16x16x32_bf16(Am, BCUR[cg*3+1], t, 0,0,0); \
        acc[cg] = t;                                                          \
      }                                                                       \
      za = na; zb = nb;                                                       \
    }

  for (int kc = 0; kc < 16; kc += 2) {
    ZSTEP(Bu, Bv, kc)
    ZSTEP(Bv, Bu, kc + 1)
  }
  #undef ZSTEP

  // bias + row-normalize (C-layout: col = cg*16+lo, row = hi*4+r)
  #pragma unroll
  for (int r = 0; r < 4; ++r) {
    float v[4], s = 0.0f;
    #pragma unroll
    for (int cg = 0; cg < 4; ++cg) {
      v[cg] = acc[cg][r] + b_in[cg * 16 + lo];
      s += v[cg] * v[cg];
    }
    s += __shfl_xor(s, 1);
    s += __shfl_xor(s, 2);
    s += __shfl_xor(s, 4);
    s += __shfl_xor(s, 8);
    float inv = rsqrtf(s * (1.0f / 64.0f) + 1e-12f);
    #pragma unroll
    for (int cg = 0; cg < 4; ++cg)
      t_lds[(hi * 4 + r) * 65 + cg * 16 + lo] = v[cg] * inv;
  }
  __syncthreads();

  // read back in A-frag order (row = lo, ks = c*32 + hi*8 + j), emit fp32+frags
  #pragma unroll
  for (int c = 0; c < 2; ++c) {
    float xs[8];
    #pragma unroll
    for (int j = 0; j < 8; ++j) xs[j] = t_lds[lo * 65 + c * 32 + hi * 8 + j];
    float* dp = zn + (size_t)(r0 + lo) * D_DIM + c * 32 + hi * 8;
    *(float4*)dp = make_float4(xs[0], xs[1], xs[2], xs[3]);
    *(float4*)(dp + 4) = make_float4(xs[4], xs[5], xs[6], xs[7]);
    bf16x8 H, M, L;
    limb3(xs, H, M, L);
    const int fb = (g * 2 + c) * 3;
    unsigned short* d0 = zn_sw + (size_t)(fb + 0) * 512 + l * 8;
    unsigned short* d1 = zn_sw + (size_t)(fb + 1) * 512 + l * 8;
    unsigned short* d2 = zn_sw + (size_t)(fb + 2) * 512 + l * 8;
    #pragma unroll
    for (int j = 0; j < 8; ++j) { d0[j] = (unsigned short)H[j]; d1[j] = (unsigned short)M[j]; d2[j] = (unsigned short)L[j]; }
  }
}

// ---------------------------------------------------------------------------
// K3 v4: MFMA argmax (unchanged from R8 — proven at 49 us).
__global__ __launch_bounds__(256, 2) void k_argmax(
    const unsigned short* __restrict__ zn_sw,
    const unsigned short* __restrict__ cn_sw,
    float* __restrict__ pval, int* __restrict__ pidx) {
  const int tid = threadIdx.x;
  const int w = tid >> 6, l = tid & 63;
  const int lo = l & 15, hi = l >> 4;
  const int gA0 = (blockIdx.x * 4 + w) * 2;   // 0..510 (16-row groups)
  const int gB0 = blockIdx.y * 64;            // B group base
  const bf16x8* Ab = (const bf16x8*)zn_sw;
  const bf16x8* Bb = (const bf16x8*)cn_sw;

  bf16x8 A0[2][3], A1[2][3];
  #pragma unroll
  for (int c = 0; c < 2; ++c)
    #pragma unroll
    for (int m = 0; m < 3; ++m) {
      A0[c][m] = Ab[(size_t)((gA0 * 2 + c) * 3 + m) * 64 + l];
      A1[c][m] = Ab[(size_t)(((gA0 + 1) * 2 + c) * 3 + m) * 64 + l];
    }

  bf16x8 Bu[2][3], Bv[2][3];
  #pragma unroll
  for (int c = 0; c < 2; ++c)
    #pragma unroll
    for (int m = 0; m < 3; ++m)
      Bu[c][m] = Bb[(size_t)((gB0 * 2 + c) * 3 + m) * 64 + l];

  float bv[8];
  int bi[8];
  #pragma unroll
  for (int i = 0; i < 8; ++i) { bv[i] = -1e30f; bi[i] = 0; }
  int cand = blockIdx.y * 1024 + lo;

  #define LOADB(dst, gB)                                                     \
    _Pragma("unroll")                                                        \
    for (int c = 0; c < 2; ++c)                                              \
      _Pragma("unroll")                                                      \
      for (int m = 0; m < 3; ++m)                                            \
        dst[c][m] = Bb[(size_t)(((gB) * 2 + c) * 3 + m) * 64 + l];

  #define COMPUTE(B)                                                          \
    {                                                                         \
      f32x4 a0 = {0.f,0.f,0.f,0.f}, a1 = {0.f,0.f,0.f,0.f};                   \
      f32x4 a2 = {0.f,0.f,0.f,0.f}, a3 = {0.f,0.f,0.f,0.f};                   \
      a0 = __builtin_amdgcn_mfma_f32_16x16x32_bf16(A0[0][0], B[0][0], a0, 0,0,0); \
      a1 = __builtin_amdgcn_mfma_f32_16x16x32_bf16(A0[1][0], B[1][0], a1, 0,0,0); \
      a2 = __builtin_amdgcn_mfma_f32_16x16x32_bf16(A1[0][0], B[0][0], a2, 0,0,0); \
      a3 = __builtin_amdgcn_mfma_f32_16x16x32_bf16(A1[1][0], B[1][0], a3, 0,0,0); \
      a0 = __builtin_amdgcn_mfma_f32_16x16x32_bf16(A0[0][0], B[0][1], a0, 0,0,0); \
      a1 = __builtin_amdgcn_mfma_f32_16x16x32_bf16(A0[1][0], B[1][1], a1, 0,0,0); \
      a2 = __builtin_amdgcn_mfma_f32_16x16x32_bf16(A1[0][0], B[0][1], a2, 0,0,0); \
      a3 = __builtin_amdgcn_mfma_f32_16x16x32_bf16(A1[1][0], B[1][1], a3, 0,0,0); \
      a0 = __builtin_amdgcn_mfma_f32_16x16x32_bf16(A0[0][1], B[0][0], a0, 0,0,0); \
      a1 = __builtin_amdgcn_mfma_f32_16x16x32_bf16(A0[1][1], B[1][0], a1, 0,0,0); \
      a2 = __builtin_amdgcn_mfma_f32_16x16x32_bf16(A1[0][1], B[0][0], a2, 0,0,0); \
      a3 = __builtin_amdgcn_mfma_f32_16x16x32_bf16(A1[1][1], B[1][0], a3, 0,0,0); \
      a0 = __builtin_amdgcn_mfma_f32_16x16x32_bf16(A0[0][0], B[0][2], a0, 0,0,0); \
      a1 = __builtin_amdgcn_mfma_f32_16x16x32_bf16(A0[1][0], B[1][2], a1, 0,0,0); \
      a2 = __builtin_amdgcn_mfma_f32_16x16x32_bf16(A1[0][0], B[0][2], a2, 0,0,0); \
      a3 = __builtin_amdgcn_mfma_f32_16x16x32_bf16(A1[1][0], B[1][2], a3, 0,0,0); \
      a0 = __builtin_amdgcn_mfma_f32_16x16x32_bf16(A0[0][2], B[0][0], a0, 0,0,0); \
      a1 = __builtin_amdgcn_mfma_f32_16x16x32_bf16(A0[1][2], B[1][0], a1, 0,0,0); \
      a2 = __builtin_amdgcn_mfma_f32_16x16x32_bf16(A1[0][2], B[0][0], a2, 0,0,0); \
      a3 = __builtin_amdgcn_mfma_f32_16x16x32_bf16(A1[1][2], B[1][0], a3, 0,0,0); \
      a0 = __builtin_amdgcn_mfma_f32_16x16x32_bf16(A0[0][1], B[0][1], a0, 0,0,0); \
      a1 = __builtin_amdgcn_mfma_f32_16x16x32_bf16(A0[1][1], B[1][1], a1, 0,0,0); \
      a2 = __builtin_amdgcn_mfma_f32_16x16x32_bf16(A1[0][1], B[0][1], a2, 0,0,0); \
      a3 = __builtin_amdgcn_mfma_f32_16x16x32_bf16(A1[1][1], B[1][1], a3, 0,0,0); \
      _Pragma("unroll")                                                       \
      for (int r = 0; r < 4; ++r) {                                           \
        float d0 = a0[r] + a1[r];                                             \
        if (d0 > bv[r]) { bv[r] = d0; bi[r] = cand; }                         \
        float d1 = a2[r] + a3[r];                                             \
        if (d1 > bv[4 + r]) { bv[4 + r] = d1; bi[4 + r] = cand; }             \
      }                                                                       \
      cand += 16;                                                             \
    }

  for (int p = 0; p < 64; p += 2) {
    LOADB(Bv, gB0 + p + 1);
    COMPUTE(Bu);
    LOADB(Bu, gB0 + p + 2);   // last iter over-reads one group into pad
    COMPUTE(Bv);
  }
  #undef LOADB
  #undef COMPUTE

  #pragma unroll
  for (int i = 0; i < 8; ++i) {
    float v = bv[i]; int ix = bi[i];
    #pragma unroll
    for (int m = 1; m < 16; m <<= 1) {
      float ov = __shfl_xor(v, m);
      int oi = __shfl_xor(ix, m);
      if (ov > v || (ov == v && oi < ix)) { v = ov; ix = oi; }
    }
    bv[i] = v; bi[i] = ix;
  }
  if (lo == 0) {
    int off = blockIdx.y * N_ROWS;
    int base0 = gA0 * 16 + hi * 4;
    int base1 = (gA0 + 1) * 16 + hi * 4;
    #pragma unroll
    for (int r = 0; r < 4; ++r) {
      pval[off + base0 + r] = bv[r];     pidx[off + base0 + r] = bi[r];
      pval[off + base1 + r] = bv[4 + r]; pidx[off + base1 + r] = bi[4 + r];
    }
  }
}

// ---------------------------------------------------------------------------
// K4 v3: fused merge + gather + loss-partial + out-GEMM. 512 blocks x 1 wave,
// ping-pong B prefetch. No LDS, no atomics.
__global__ __launch_bounds__(64) void k_out(
    const float* __restrict__ cn, const float* __restrict__ zn,
    const float* __restrict__ pval, const int* __restrict__ pidx,
    const unsigned short* __restrict__ w_out_sw,
    const float* __restrict__ b_out, float* __restrict__ out,
    float* __restrict__ idx_f, float* __restrict__ pl) {
  const int l = threadIdx.x;
  const int lo = l & 15, hi = l >> 4;
  const int r0 = blockIdx.x * 16;
  const int row = r0 + lo;

  // merge 8 code-eighth partials (ascending q + strict > => lowest index)
  float v = pval[row];
  int ix = pidx[row];
  #pragma unroll
  for (int q = 1; q < 8; ++q) {
    float vq = pval[q * N_ROWS + row];
    int iq = pidx[q * N_ROWS + row];
    if (vq > v) { v = vq; ix = iq; }
  }
  if (hi == 0) idx_f[row] = (float)ix;

  // gather cn[ix], zn[row] in A-frag order; limb-split; loss partial
  bf16x8 A[2][3];
  float lp = 0.0f;
  #pragma unroll
  for (int c = 0; c < 2; ++c) {
    const float* cp = cn + (size_t)ix * D_DIM + c * 32 + hi * 8;
    const float* zp = zn + (size_t)row * D_DIM + c * 32 + hi * 8;
    float4 c0 = *(const float4*)cp, c1 = *(const float4*)(cp + 4);
    float4 z0 = *(const float4*)zp, z1 = *(const float4*)(zp + 4);
    float xs[8] = {c0.x, c0.y, c0.z, c0.w, c1.x, c1.y, c1.z, c1.w};
    float zs[8] = {z0.x, z0.y, z0.z, z0.w, z1.x, z1.y, z1.z, z1.w};
    limb3(xs, A[c][0], A[c][1], A[c][2]);
    #pragma unroll
    for (int j = 0; j < 8; ++j) { float d = xs[j] - zs[j]; lp += d * d; }
  }
  #pragma unroll
  for (int m = 1; m < 64; m <<= 1) lp += __shfl_xor(lp, m);
  if (l == 0) pl[blockIdx.x] = lp;

  const bf16x8* Bptr = (const bf16x8*)w_out_sw;
  bf16x8 Bu[6], Bv[6];
  #pragma unroll
  for (int i = 0; i < 6; ++i) Bu[i] = Bptr[(size_t)i * 64 + l];

  #define OSTEP(BCUR, BNXT, CG)                                               \
    {                                                                         \
      _Pragma("unroll")                                                       \
      for (int i = 0; i < 6; ++i)                                             \
        BNXT[i] = Bptr[((size_t)((CG) + 1) * 6 + i) * 64 + l];                \
      f32x4 a0 = {0.f,0.f,0.f,0.f}, a1 = {0.f,0.f,0.f,0.f};                   \
      a0 = __builtin_amdgcn_mfma_f32_16x16x32_bf16(A[0][0], BCUR[0], a0, 0,0,0); \
      a1 = __builtin_amdgcn_mfma_f32_16x16x32_bf16(A[1][0], BCUR[3], a1, 0,0,0); \
      a0 = __builtin_amdgcn_mfma_f32_16x16x32_bf16(A[0][0], BCUR[1], a0, 0,0,0); \
      a1 = __builtin_amdgcn_mfma_f32_16x16x32_bf16(A[1][0], BCUR[4], a1, 0,0,0); \
      a0 = __builtin_amdgcn_mfma_f32_16x16x32_bf16(A[0][1], BCUR[0], a0, 0,0,0); \
      a1 = __builtin_amdgcn_mfma_f32_16x16x32_bf16(A[1][1], BCUR[3], a1, 0,0,0); \
      a0 = __builtin_amdgcn_mfma_f32_16x16x32_bf16(A[0][0], BCUR[2], a0, 0,0,0); \
      a1 = __builtin_amdgcn_mfma_f32_16x16x32_bf16(A[1][0], BCUR[5], a1, 0,0,0); \
      a0 = __builtin_amdgcn_mfma_f32_16x16x32_bf16(A[0][2], BCUR[0], a0, 0,0,0); \
      a1 = __builtin_amdgcn_mfma_f32_16x16x32_bf16(A[1][2], BCUR[3], a1, 0,0,0); \
      a0 = __builtin_amdgcn_mfma_f32_16x16x32_bf16(A[0][1], BCUR[1], a0, 0,0,0); \
      a1 = __builtin_amdgcn_mfma_f32_16x16x32_bf16(A[1][1], BCUR[4], a1, 0,0,0); \
      float bb = b_out[(CG) * 16 + lo];                                       \
      _Pragma("unroll")                                                       \
      for (int r = 0; r < 4; ++r)                                             \
        out[(size_t)(r0 + hi * 4 + r) * F_DIM + (CG) * 16 + lo] =             \
            a0[r] + a1[r] + bb;                                               \
    }

  for (int cg = 0; cg < 32; cg += 2) {
    OSTEP(Bu, Bv, cg)          // cg=31's prefetch over-reads 6KB past wout_sw
    OSTEP(Bv, Bu, cg + 1)      // (lands in pval scratch - harmless reads)
  }
  #undef OSTEP
}

// ---------------------------------------------------------------------------
// K5 v2: sum 512 loss partials -> final loss (one wave).
__global__ __launch_bounds__(64) void k_loss_final(
    const float* __restrict__ pl, float* __restrict__ loss_out) {
  const int l = threadIdx.x;
  float s = 0.0f;
  #pragma unroll
  for (int i = 0; i < 8; ++i) s += pl[l + 64 * i];
  #pragma unroll
  for (int m = 1; m < 64; m <<= 1) s += __shfl_xor(s, m);
  if (l == 0) loss_out[0] = s * (1.25f / (float)(N_ROWS * D_DIM));
}

// ---------------------------------------------------------------------------
extern "C" void kernel_launch(void* const* d_in, const int* in_sizes, int n_in,
                              void* d_out, int out_size, void* d_ws, size_t ws_size,
                              hipStream_t stream) {
  const float* z        = (const float*)d_in[0];
  const float* W_in     = (const float*)d_in[1];
  const float* b_in     = (const float*)d_in[2];
  const float* codebook = (const float*)d_in[3];
  const float* W_out    = (const float*)d_in[4];
  const float* b_out    = (const float*)d_in[5];

  float* outp   = (float*)d_out;                      // Output 0: [8192 x 512]
  float* loss_f = outp + (size_t)N_ROWS * F_DIM;      // Output 1
  float* idx_f  = loss_f + 1;                         // Output 2

  // workspace layout (float units)
  float* wsf = (float*)d_ws;
  float* zn_ws = wsf;                                         // [0, 524288)
  float* cn_ws = wsf + 524288;                                // [524288, 1048576)
  unsigned short* zn_sw = (unsigned short*)(wsf + 1048576);   // 786432 f
  unsigned short* cn_sw = (unsigned short*)(wsf + 1835008);   // 786432 f, ends 2621440
  // 16 KB pad @ [2621440, 2625536) for argmax B over-read
  unsigned short* win_sw  = (unsigned short*)(wsf + 2625536); // 49152 f
  unsigned short* wout_sw = (unsigned short*)(wsf + 2674688); // 49152 f
  float* pval_ws = wsf + 2723840;                             // 65536 f (8 x 8192)
  int*   pidx_ws = (int*)(wsf + 2789376);                     // 65536 ints
  float* pl_ws   = wsf + 2854912;                             // 512 f
  // total 2855424 floats ~ 11.4 MB

  hipLaunchKernelGGL(k_swz_win, dim3(16), dim3(256), 0, stream, W_in, win_sw);
  hipLaunchKernelGGL(k_swz_wout, dim3(16), dim3(256), 0, stream, W_out, wout_sw);
  hipLaunchKernelGGL(k_cn, dim3(128), dim3(256), 0, stream,
                     codebook, cn_ws, cn_sw);
  hipLaunchKernelGGL(k_zn, dim3(512), dim3(64), 0, stream,
                     z, win_sw, b_in, zn_ws, zn_sw);
  hipLaunchKernelGGL(k_argmax, dim3(64, 8), dim3(256), 0, stream,
                     zn_sw, cn_sw, pval_ws, pidx_ws);
  hipLaunchKernelGGL(k_out, dim3(512), dim3(64), 0, stream,
                     cn_ws, zn_ws, pval_ws, pidx_ws, wout_sw, b_out,
                     outp, idx_f, pl_ws);
  hipLaunchKernelGGL(k_loss_final, dim3(1), dim3(64), 0, stream,
                     pl_ws, loss_f);
}